// Round 7
// baseline (1982.438 us; speedup 1.0000x reference)
//
#include <hip/hip_runtime.h>

#define N_RAYS 16384
#define NSAMP  96
#define GD 128
#define GH 128
#define GW 128
#define C_IN  32
#define C_HID 32
#define C_OUT 16
#define M_PTS (N_RAYS * NSAMP)       // 1,572,864 (divisible by 256)
#define TPA 16                        // tiles per axis (128/8)
#define NTILES (TPA*TPA*TPA)          // 4096
#define TW 8                          // tile width (voxels)
#define TVOX (TW*TW*TW)               // 512 voxels per tile
#define CHUNK 128                     // entries staged per K4 inner pass

__device__ __forceinline__ int clampi(int v, int hi) { return min(max(v, 0), hi); }

struct TileSpan { int txa, txb, tya, tyb, tza, tzb; };
__device__ __forceinline__ TileSpan tile_span(int X, int Y, int Z) {
    TileSpan s;
    s.txa = clampi(X,   GW-1) >> 3;  s.txb = clampi(X+1, GW-1) >> 3;
    s.tya = clampi(Y,   GH-1) >> 3;  s.tyb = clampi(Y+1, GH-1) >> 3;
    s.tza = clampi(Z,   GD-1) >> 3;  s.tzb = clampi(Z+1, GD-1) >> 3;
    return s;
}

// ============================================================================
// K1: per-point gather + MLP. Stores o[16] (planar float4) + frac/key, and
// accumulates per-tile point counts (LDS histogram -> global atomicAdd).
// ============================================================================
__global__ __launch_bounds__(256) void k1_point(
    const float* __restrict__ origins, const float* __restrict__ dirs,
    const float* __restrict__ nearv,   const float* __restrict__ farv,
    const float* __restrict__ enc,     const int*   __restrict__ gidx,
    const float* __restrict__ grid,    const float* __restrict__ W0,
    const float* __restrict__ b0,      const float* __restrict__ W1,
    const float* __restrict__ b1,
    float4* __restrict__ pf, float4* __restrict__ po, unsigned* __restrict__ counts)
{
    __shared__ unsigned lcnt[NTILES];
    for (int i = threadIdx.x; i < NTILES; i += 256) lcnt[i] = 0;
    __syncthreads();

    int pid = blockIdx.x * 256 + threadIdx.x;     // always < M_PTS (exact grid)
    int ray = pid / NSAMP;
    int s   = pid - ray * NSAMP;

    float nr = nearv[ray], fr = farv[ray];
    float t  = nr + (fr - nr) * ((float)s * (1.0f / (NSAMP - 1)));
    float px = fmaf(t, dirs[ray*3+0], origins[ray*3+0]);
    float py = fmaf(t, dirs[ray*3+1], origins[ray*3+1]);
    float pz = fmaf(t, dirs[ray*3+2], origins[ray*3+2]);
    int   b  = gidx[ray];

    float cx = ((px + 1.0f) * (float)GW - 1.0f) * 0.5f;
    float cy = ((py + 1.0f) * (float)GH - 1.0f) * 0.5f;
    float cz = ((pz + 1.0f) * (float)GD - 1.0f) * 0.5f;
    float fxf = floorf(cx), fyf = floorf(cy), fzf = floorf(cz);
    float fx = cx - fxf, fy = cy - fyf, fz = cz - fzf;
    int X = (int)fxf, Y = (int)fyf, Z = (int)fzf;

    // ---- trilinear gather (feat starts at ray encoding) ----
    float feat[C_IN];
    {
        const float4* e4 = (const float4*)(enc + (size_t)ray * C_IN);
        #pragma unroll
        for (int q = 0; q < C_IN/4; ++q) {
            float4 v = e4[q];
            feat[4*q+0] = v.x; feat[4*q+1] = v.y; feat[4*q+2] = v.z; feat[4*q+3] = v.w;
        }
    }
    int gx[2] = { clampi(X, GW-1), clampi(X+1, GW-1) };
    int gy[2] = { clampi(Y, GH-1), clampi(Y+1, GH-1) };
    int gz[2] = { clampi(Z, GD-1), clampi(Z+1, GD-1) };
    float wxa[2] = { 1.0f - fx, fx };
    float wya[2] = { 1.0f - fy, fy };
    float wza[2] = { 1.0f - fz, fz };
    #pragma unroll
    for (int dz = 0; dz < 2; ++dz)
    #pragma unroll
    for (int dy = 0; dy < 2; ++dy)
    #pragma unroll
    for (int dx = 0; dx < 2; ++dx) {
        float w = wza[dz] * wya[dy] * wxa[dx];
        size_t flat = ((((size_t)b * GD + gz[dz]) * GH + gy[dy]) * GW + gx[dx]) * C_IN;
        const float4* g4 = (const float4*)(grid + flat);
        #pragma unroll
        for (int q = 0; q < C_IN/4; ++q) {
            float4 v = g4[q];
            feat[4*q+0] = fmaf(w, v.x, feat[4*q+0]);
            feat[4*q+1] = fmaf(w, v.y, feat[4*q+1]);
            feat[4*q+2] = fmaf(w, v.z, feat[4*q+2]);
            feat[4*q+3] = fmaf(w, v.w, feat[4*q+3]);
        }
    }

    // ---- MLP (weights wave-uniform -> scalar loads) ----
    float h[C_HID];
    #pragma unroll
    for (int j = 0; j < C_HID; ++j) h[j] = b0[j];
    #pragma unroll
    for (int i = 0; i < C_IN; ++i) {
        float xi = feat[i];
        #pragma unroll
        for (int j = 0; j < C_HID; ++j) h[j] = fmaf(xi, W0[i*C_HID + j], h[j]);
    }
    #pragma unroll
    for (int j = 0; j < C_HID; ++j) h[j] = fmaxf(h[j], 0.0f);

    float o[C_OUT];
    #pragma unroll
    for (int j = 0; j < C_OUT; ++j) o[j] = b1[j];
    #pragma unroll
    for (int i = 0; i < C_HID; ++i) {
        float hi = h[i];
        #pragma unroll
        for (int j = 0; j < C_OUT; ++j) o[j] = fmaf(hi, W1[i*C_OUT + j], o[j]);
    }

    // ---- store point record (planar, coalesced) ----
    unsigned key = ((unsigned)(X + 256) & 511u)
                 | (((unsigned)(Y + 256) & 511u) << 9)
                 | (((unsigned)(Z + 256) & 511u) << 18);
    pf[pid] = make_float4(fx, fy, fz, __uint_as_float(key));
    #pragma unroll
    for (int q = 0; q < 4; ++q)
        po[(size_t)q * M_PTS + pid] = make_float4(o[4*q+0], o[4*q+1], o[4*q+2], o[4*q+3]);

    // ---- count touched tiles ----
    TileSpan ts = tile_span(X, Y, Z);
    #pragma unroll
    for (int ez = 0; ez < 2; ++ez) {
        if (ez && ts.tzb == ts.tza) continue;
        #pragma unroll
        for (int ey = 0; ey < 2; ++ey) {
            if (ey && ts.tyb == ts.tya) continue;
            #pragma unroll
            for (int ex = 0; ex < 2; ++ex) {
                if (ex && ts.txb == ts.txa) continue;
                int tt = ((ts.tza + ez) * TPA + (ts.tya + ey)) * TPA + (ts.txa + ex);
                atomicAdd(&lcnt[tt], 1u);
            }
        }
    }
    __syncthreads();
    for (int i = threadIdx.x; i < NTILES; i += 256)
        if (lcnt[i]) atomicAdd(&counts[i], lcnt[i]);
}

// ============================================================================
// K2: exclusive scan of 4096 tile counts (single block, simple & correct).
// ============================================================================
__global__ __launch_bounds__(256) void k2_scan(
    const unsigned* __restrict__ counts,
    unsigned* __restrict__ offsets, unsigned* __restrict__ alloc)
{
    __shared__ unsigned psum[256];
    int tid = threadIdx.x;
    unsigned base = tid * 16;
    unsigned ssum = 0;
    for (int i = 0; i < 16; ++i) ssum += counts[base + i];
    psum[tid] = ssum;
    __syncthreads();
    if (tid == 0) {
        unsigned r = 0;
        for (int i = 0; i < 256; ++i) { unsigned v = psum[i]; psum[i] = r; r += v; }
    }
    __syncthreads();
    unsigned run = psum[tid];
    for (int i = 0; i < 16; ++i) {
        unsigned v = counts[base + i];
        offsets[base + i] = run;
        alloc[base + i]   = run;
        run += v;
    }
}

// ============================================================================
// K3: scatter point indices into per-tile segments. Block-local LDS histogram
// + rank, one global atomicAdd per (block, nonzero tile) for segment alloc.
// ============================================================================
__global__ __launch_bounds__(256) void k3_scatter(
    const float4* __restrict__ pf, unsigned* __restrict__ alloc,
    unsigned* __restrict__ entries)
{
    __shared__ unsigned lcnt[NTILES];
    __shared__ unsigned lbase[NTILES];
    for (int i = threadIdx.x; i < NTILES; i += 256) lcnt[i] = 0;
    __syncthreads();

    int pid = blockIdx.x * 256 + threadIdx.x;
    float4 f = pf[pid];
    unsigned key = __float_as_uint(f.w);
    int X = (int)(key & 511u) - 256;
    int Y = (int)((key >> 9) & 511u) - 256;
    int Z = (int)((key >> 18) & 511u) - 256;
    TileSpan ts = tile_span(X, Y, Z);

    unsigned rnk[2][2][2];
    #pragma unroll
    for (int ez = 0; ez < 2; ++ez) {
        bool okz = (ez == 0) || (ts.tzb > ts.tza);
        #pragma unroll
        for (int ey = 0; ey < 2; ++ey) {
            bool oky = (ey == 0) || (ts.tyb > ts.tya);
            #pragma unroll
            for (int ex = 0; ex < 2; ++ex) {
                bool okx = (ex == 0) || (ts.txb > ts.txa);
                if (okz && oky && okx) {
                    int tt = ((ts.tza + ez) * TPA + (ts.tya + ey)) * TPA + (ts.txa + ex);
                    rnk[ez][ey][ex] = atomicAdd(&lcnt[tt], 1u);
                }
            }
        }
    }
    __syncthreads();
    for (int i = threadIdx.x; i < NTILES; i += 256)
        if (lcnt[i]) lbase[i] = atomicAdd(&alloc[i], lcnt[i]);
    __syncthreads();
    #pragma unroll
    for (int ez = 0; ez < 2; ++ez) {
        bool okz = (ez == 0) || (ts.tzb > ts.tza);
        #pragma unroll
        for (int ey = 0; ey < 2; ++ey) {
            bool oky = (ey == 0) || (ts.tyb > ts.tya);
            #pragma unroll
            for (int ex = 0; ex < 2; ++ex) {
                bool okx = (ex == 0) || (ts.txb > ts.txa);
                if (okz && oky && okx) {
                    int tt = ((ts.tza + ez) * TPA + (ts.tya + ey)) * TPA + (ts.txa + ex);
                    entries[lbase[tt] + rnk[ez][ey][ex]] = (unsigned)pid;
                }
            }
        }
    }
}

// ============================================================================
// K4 (REWRITTEN): entry-per-wave, lane = (corner dy,dx) x (channel).
// Stage CHUNK entries coalesced into LDS, then each wave processes entries
// (strided across 4 waves). Per entry: every lane owns one (corner,channel)
// pair (dz covered by a 2-iter loop) -> ONE predicated ds_add each, with
// per-instruction addresses all distinct (2 lanes/bank = free). ~70% lane
// utilization vs ~3% in the voxel-stationary gather. Dense writeback.
// ============================================================================
__global__ __launch_bounds__(256) void k4_accum(
    const float4* __restrict__ pf, const float4* __restrict__ po,
    const unsigned* __restrict__ entries, const unsigned* __restrict__ offsets,
    const unsigned* __restrict__ alloc, float* __restrict__ out)
{
    __shared__ float  acc[TVOX * C_OUT];   // [voxel][ch], 32 KB
    __shared__ float4 sA[CHUNK];           // fx, fy, fz, packed cx0|cx1|cy0|cy1
    __shared__ int    sZ[CHUNK];           // cz0 | cz1<<8
    __shared__ float  sOT[CHUNK * 17];     // o[16] transposed, +1 pad (bank-free)

    int t  = blockIdx.x;
    int tx = t & (TPA-1), ty = (t >> 4) & (TPA-1), tz = t >> 8;
    int ox = tx * TW, oy = ty * TW, oz = tz * TW;

    int tid  = threadIdx.x;
    int lane = tid & 63;
    int wv   = tid >> 6;

    for (int i = tid; i < TVOX * C_OUT; i += 256) acc[i] = 0.0f;

    // lane-constant corner bits (dy,dx) and channel
    int ch = lane & 15;
    int dx = (lane >> 4) & 1;
    int dy = (lane >> 5) & 1;

    unsigned e0 = offsets[t], e1 = alloc[t];
    for (unsigned base = e0; base < e1; base += CHUNK) {
        int n = min((unsigned)CHUNK, e1 - base);
        if (tid < n) {
            unsigned p = entries[base + tid];
            float4 f = pf[p];
            unsigned key = __float_as_uint(f.w);
            int X = (int)(key & 511u) - 256;
            int Y = (int)((key >> 9) & 511u) - 256;
            int Z = (int)((key >> 18) & 511u) - 256;
            unsigned pk = (unsigned)clampi(X, GW-1)        |
                          ((unsigned)clampi(X+1, GW-1)<<8) |
                          ((unsigned)clampi(Y, GH-1)<<16)  |
                          ((unsigned)clampi(Y+1, GH-1)<<24);
            sA[tid] = make_float4(f.x, f.y, f.z, __uint_as_float(pk));
            sZ[tid] = clampi(Z, GD-1) | (clampi(Z+1, GD-1) << 8);
            #pragma unroll
            for (int q = 0; q < 4; ++q) {
                float4 ov = po[(size_t)q * M_PTS + p];
                sOT[tid*17 + 4*q+0] = ov.x;
                sOT[tid*17 + 4*q+1] = ov.y;
                sOT[tid*17 + 4*q+2] = ov.z;
                sOT[tid*17 + 4*q+3] = ov.w;
            }
        }
        __syncthreads();

        // wave wv processes entries wv, wv+4, wv+8, ... (spreads same-ray runs)
        for (int j = wv; j < n; j += 4) {
            float4 a = sA[j];                   // uniform per wave -> broadcast
            unsigned pk = __float_as_uint(a.w);
            int pz = sZ[j];
            float oc = sOT[j*17 + ch];          // 16 addrs, 4-way broadcast

            int cx0 = (int)(pk & 255u),        cx1 = (int)((pk >> 8) & 255u);
            int cy0 = (int)((pk >> 16) & 255u), cy1 = (int)(pk >> 24);
            int cz0 = pz & 255,                cz1 = (pz >> 8) & 255;

            int   vx = dx ? cx1 : cx0;
            int   vy = dy ? cy1 : cy0;
            float wx = dx ? a.x : 1.0f - a.x;
            float wy = dy ? a.y : 1.0f - a.y;
            float wo = wx * wy * oc;

            int ux = vx - ox, uy = vy - oy;
            bool inxy = ((unsigned)ux < (unsigned)TW) & ((unsigned)uy < (unsigned)TW);
            int lbase = (uy * TW + ux) * C_OUT + ch;

            #pragma unroll
            for (int pass = 0; pass < 2; ++pass) {
                int   vz = pass ? cz1 : cz0;
                float wz = pass ? a.z : 1.0f - a.z;
                int   uz = vz - oz;
                if (inxy & ((unsigned)uz < (unsigned)TW))
                    atomicAdd(&acc[uz * (TW*TW*C_OUT) + lbase], wo * wz);
            }
        }
        __syncthreads();
    }

    // ---- dense writeback: acc [voxel][ch] matches out layout directly ----
    for (int i = tid; i < (TVOX * C_OUT) / 4; i += 256) {
        int lin = i * 4;
        int c4  = lin & (C_OUT - 1);
        int v   = lin >> 4;
        int vx = v & (TW-1), vy = (v >> 3) & (TW-1), vz = v >> 6;
        size_t oaddr = ((((size_t)(oz + vz)) * GH + (oy + vy)) * GW + (ox + vx)) * C_OUT + c4;
        *(float4*)(out + oaddr) = *(const float4*)(acc + lin);
    }
}

// ============================================================================
// Fallback (round-3 fused kernel) if workspace is too small.
// ============================================================================
#define SEGS   8
#define SEGLEN (NSAMP / SEGS)
#define NTHREADS (N_RAYS * SEGS)

__global__ __launch_bounds__(256, 2) void splat_seg_kernel(
    const float* __restrict__ origins, const float* __restrict__ dirs,
    const float* __restrict__ nearv,   const float* __restrict__ farv,
    const float* __restrict__ enc,     const int*   __restrict__ gidx,
    const float* __restrict__ grid,    const float* __restrict__ W0,
    const float* __restrict__ b0,      const float* __restrict__ W1,
    const float* __restrict__ b1,      float* __restrict__ out)
{
    int tid = blockIdx.x * blockDim.x + threadIdx.x;
    if (tid >= NTHREADS) return;
    int ray = tid / SEGS;
    int seg = tid - ray * SEGS;
    float nr = nearv[ray], fr = farv[ray];
    float ox = origins[3*ray+0], oy = origins[3*ray+1], oz = origins[3*ray+2];
    float rdx = dirs[3*ray+0],   rdy = dirs[3*ray+1],   rdz = dirs[3*ray+2];
    int   b  = gidx[ray];
    float accv[8][C_OUT];
    #pragma unroll
    for (int sl = 0; sl < 8; ++sl)
        #pragma unroll
        for (int c = 0; c < C_OUT; ++c) accv[sl][c] = 0.0f;
    int Xp = 0, Yp = 0, Zp = 0;
    #pragma unroll 1
    for (int k = 0; k < SEGLEN; ++k) {
        int s = seg * SEGLEN + k;
        float t  = nr + (fr - nr) * ((float)s * (1.0f / (NSAMP - 1)));
        float px = fmaf(t, rdx, ox);
        float py = fmaf(t, rdy, oy);
        float pz = fmaf(t, rdz, oz);
        float cx = ((px + 1.0f) * (float)GW - 1.0f) * 0.5f;
        float cy = ((py + 1.0f) * (float)GH - 1.0f) * 0.5f;
        float cz = ((pz + 1.0f) * (float)GD - 1.0f) * 0.5f;
        float fxf = floorf(cx), fyf = floorf(cy), fzf = floorf(cz);
        float fx = cx - fxf, fy = cy - fyf, fz = cz - fzf;
        int X = (int)fxf, Y = (int)fyf, Z = (int)fzf;
        if (k == 0) { Xp = X; Yp = Y; Zp = Z; }
        else if (X != Xp || Y != Yp || Z != Zp) {
            bool fXm[2], fYm[2], fZm[2];
            int  vx[2], vy[2], vz[2];
            #pragma unroll
            for (int p = 0; p < 2; ++p) {
                int xo = Xp + ((Xp ^ p) & 1), xn = X + ((X ^ p) & 1);
                fXm[p] = (xo != xn);  vx[p] = clampi(xo, GW-1);
                int yo = Yp + ((Yp ^ p) & 1), yn = Y + ((Y ^ p) & 1);
                fYm[p] = (yo != yn);  vy[p] = clampi(yo, GH-1);
                int zo = Zp + ((Zp ^ p) & 1), zn = Z + ((Z ^ p) & 1);
                fZm[p] = (zo != zn);  vz[p] = clampi(zo, GD-1);
            }
            #pragma unroll
            for (int pxi = 0; pxi < 2; ++pxi)
            #pragma unroll
            for (int pyi = 0; pyi < 2; ++pyi)
            #pragma unroll
            for (int pzi = 0; pzi < 2; ++pzi) {
                const int sl = pxi*4 + pyi*2 + pzi;
                if (fXm[pxi] | fYm[pyi] | fZm[pzi]) {
                    size_t flat = ((((size_t)b * GD + vz[pzi]) * GH + vy[pyi]) * GW + vx[pxi]) * C_OUT;
                    float* op = out + flat;
                    #pragma unroll
                    for (int c = 0; c < C_OUT; ++c) { atomicAdd(op + c, accv[sl][c]); accv[sl][c] = 0.0f; }
                }
            }
            Xp = X; Yp = Y; Zp = Z;
        }
        float feat[C_IN];
        {
            const float4* e4 = (const float4*)(enc + (size_t)ray * C_IN);
            #pragma unroll
            for (int q = 0; q < C_IN/4; ++q) {
                float4 v = e4[q];
                feat[4*q+0] = v.x; feat[4*q+1] = v.y; feat[4*q+2] = v.z; feat[4*q+3] = v.w;
            }
        }
        int gx[2] = { clampi(X, GW-1), clampi(X+1, GW-1) };
        int gy[2] = { clampi(Y, GH-1), clampi(Y+1, GH-1) };
        int gz[2] = { clampi(Z, GD-1), clampi(Z+1, GD-1) };
        float wxa[2] = { 1.0f - fx, fx };
        float wya[2] = { 1.0f - fy, fy };
        float wza[2] = { 1.0f - fz, fz };
        #pragma unroll
        for (int dz = 0; dz < 2; ++dz)
        #pragma unroll
        for (int dy = 0; dy < 2; ++dy)
        #pragma unroll
        for (int dx = 0; dx < 2; ++dx) {
            float w = wza[dz] * wya[dy] * wxa[dx];
            size_t flat = ((((size_t)b * GD + gz[dz]) * GH + gy[dy]) * GW + gx[dx]) * C_IN;
            const float4* g4 = (const float4*)(grid + flat);
            #pragma unroll
            for (int q = 0; q < C_IN/4; ++q) {
                float4 v = g4[q];
                feat[4*q+0] = fmaf(w, v.x, feat[4*q+0]);
                feat[4*q+1] = fmaf(w, v.y, feat[4*q+1]);
                feat[4*q+2] = fmaf(w, v.z, feat[4*q+2]);
                feat[4*q+3] = fmaf(w, v.w, feat[4*q+3]);
            }
        }
        float h[C_HID];
        #pragma unroll
        for (int j = 0; j < C_HID; ++j) h[j] = b0[j];
        #pragma unroll
        for (int i = 0; i < C_IN; ++i) {
            float xi = feat[i];
            #pragma unroll
            for (int j = 0; j < C_HID; ++j) h[j] = fmaf(xi, W0[i*C_HID + j], h[j]);
        }
        #pragma unroll
        for (int j = 0; j < C_HID; ++j) h[j] = fmaxf(h[j], 0.0f);
        float o[C_OUT];
        #pragma unroll
        for (int j = 0; j < C_OUT; ++j) o[j] = b1[j];
        #pragma unroll
        for (int i = 0; i < C_HID; ++i) {
            float hi = h[i];
            #pragma unroll
            for (int j = 0; j < C_OUT; ++j) o[j] = fmaf(hi, W1[i*C_OUT + j], o[j]);
        }
        float wxs[2], wys[2], wzs[2];
        #pragma unroll
        for (int p = 0; p < 2; ++p) {
            wxs[p] = ((X & 1) == p) ? (1.0f - fx) : fx;
            wys[p] = ((Y & 1) == p) ? (1.0f - fy) : fy;
            wzs[p] = ((Z & 1) == p) ? (1.0f - fz) : fz;
        }
        #pragma unroll
        for (int pxi = 0; pxi < 2; ++pxi)
        #pragma unroll
        for (int pyi = 0; pyi < 2; ++pyi)
        #pragma unroll
        for (int pzi = 0; pzi < 2; ++pzi) {
            const int sl = pxi*4 + pyi*2 + pzi;
            float w = wxs[pxi] * wys[pyi] * wzs[pzi];
            #pragma unroll
            for (int c = 0; c < C_OUT; ++c) accv[sl][c] = fmaf(w, o[c], accv[sl][c]);
        }
    }
    #pragma unroll
    for (int pxi = 0; pxi < 2; ++pxi)
    #pragma unroll
    for (int pyi = 0; pyi < 2; ++pyi)
    #pragma unroll
    for (int pzi = 0; pzi < 2; ++pzi) {
        const int sl = pxi*4 + pyi*2 + pzi;
        int vx = clampi(Xp + ((Xp ^ pxi) & 1), GW-1);
        int vy = clampi(Yp + ((Yp ^ pyi) & 1), GH-1);
        int vz = clampi(Zp + ((Zp ^ pzi) & 1), GD-1);
        size_t flat = ((((size_t)b * GD + vz) * GH + vy) * GW + vx) * C_OUT;
        float* op = out + flat;
        #pragma unroll
        for (int c = 0; c < C_OUT; ++c) atomicAdd(op + c, accv[sl][c]);
    }
}

// ============================================================================
extern "C" void kernel_launch(void* const* d_in, const int* in_sizes, int n_in,
                              void* d_out, int out_size, void* d_ws, size_t ws_size,
                              hipStream_t stream) {
    const float* origins = (const float*)d_in[0];
    const float* dirs    = (const float*)d_in[1];
    const float* nearv   = (const float*)d_in[2];
    const float* farv    = (const float*)d_in[3];
    const float* enc     = (const float*)d_in[4];
    const int*   gidx    = (const int*)  d_in[5];
    const float* grid    = (const float*)d_in[6];
    const float* W0      = (const float*)d_in[7];
    const float* b0      = (const float*)d_in[8];
    const float* W1      = (const float*)d_in[9];
    const float* b1      = (const float*)d_in[10];
    float* out = (float*)d_out;

    const size_t PF_B = (size_t)M_PTS * 16;         // 25,165,824
    const size_t PO_B = (size_t)M_PTS * 64;         // 100,663,296
    const size_t EN_B = (size_t)M_PTS * 8 * 4;      // 50,331,648 (hard bound)
    const size_t CT_B = (size_t)NTILES * 4;
    const size_t NEED = PF_B + PO_B + EN_B + 3 * CT_B;

    if (ws_size < NEED) {
        // fallback: fused register-merged scatter (round-3 path)
        hipMemsetAsync(out, 0, (size_t)out_size * sizeof(float), stream);
        splat_seg_kernel<<<NTHREADS/256, 256, 0, stream>>>(
            origins, dirs, nearv, farv, enc, gidx, grid, W0, b0, W1, b1, out);
        return;
    }

    char* w = (char*)d_ws;
    float4*   pf      = (float4*)   w;              w += PF_B;
    float4*   po      = (float4*)   w;              w += PO_B;
    unsigned* entries = (unsigned*) w;              w += EN_B;
    unsigned* counts  = (unsigned*) w;              w += CT_B;
    unsigned* offsets = (unsigned*) w;              w += CT_B;
    unsigned* alloc   = (unsigned*) w;              w += CT_B;

    hipMemsetAsync(counts, 0, CT_B, stream);
    k1_point<<<M_PTS/256, 256, 0, stream>>>(origins, dirs, nearv, farv, enc, gidx,
                                            grid, W0, b0, W1, b1, pf, po, counts);
    k2_scan<<<1, 256, 0, stream>>>(counts, offsets, alloc);
    k3_scatter<<<M_PTS/256, 256, 0, stream>>>(pf, alloc, entries);
    k4_accum<<<NTILES, 256, 0, stream>>>(pf, po, entries, offsets, alloc, out);
    // K4 writes every output voxel densely -> no output memset needed.
}

// Round 8
// 1173.290 us; speedup vs baseline: 1.6896x; 1.6896x over previous
//
#include <hip/hip_runtime.h>

#define N_RAYS 16384
#define NSAMP  96
#define GD 128
#define GH 128
#define GW 128
#define C_IN  32
#define C_HID 32
#define C_OUT 16
#define M_PTS (N_RAYS * NSAMP)       // 1,572,864 (divisible by 256)
#define TPA 16                        // tiles per axis (128/8)
#define NTILES (TPA*TPA*TPA)          // 4096
#define TW 8                          // tile width (voxels)
#define TVOX (TW*TW*TW)               // 512 voxels per tile
#define CHUNK 128                     // entries staged per K4 inner pass

__device__ __forceinline__ int clampi(int v, int hi) { return min(max(v, 0), hi); }

struct TileSpan { int txa, txb, tya, tyb, tza, tzb; };
__device__ __forceinline__ TileSpan tile_span(int X, int Y, int Z) {
    TileSpan s;
    s.txa = clampi(X,   GW-1) >> 3;  s.txb = clampi(X+1, GW-1) >> 3;
    s.tya = clampi(Y,   GH-1) >> 3;  s.tyb = clampi(Y+1, GH-1) >> 3;
    s.tza = clampi(Z,   GD-1) >> 3;  s.tzb = clampi(Z+1, GD-1) >> 3;
    return s;
}

// ============================================================================
// K1: per-point gather + MLP. Stores o[16] (planar float4) + frac/key, and
// accumulates per-tile point counts (LDS histogram -> global atomicAdd).
// ============================================================================
__global__ __launch_bounds__(256) void k1_point(
    const float* __restrict__ origins, const float* __restrict__ dirs,
    const float* __restrict__ nearv,   const float* __restrict__ farv,
    const float* __restrict__ enc,     const int*   __restrict__ gidx,
    const float* __restrict__ grid,    const float* __restrict__ W0,
    const float* __restrict__ b0,      const float* __restrict__ W1,
    const float* __restrict__ b1,
    float4* __restrict__ pf, float4* __restrict__ po, unsigned* __restrict__ counts)
{
    __shared__ unsigned lcnt[NTILES];
    for (int i = threadIdx.x; i < NTILES; i += 256) lcnt[i] = 0;
    __syncthreads();

    int pid = blockIdx.x * 256 + threadIdx.x;     // always < M_PTS (exact grid)
    int ray = pid / NSAMP;
    int s   = pid - ray * NSAMP;

    float nr = nearv[ray], fr = farv[ray];
    float t  = nr + (fr - nr) * ((float)s * (1.0f / (NSAMP - 1)));
    float px = fmaf(t, dirs[ray*3+0], origins[ray*3+0]);
    float py = fmaf(t, dirs[ray*3+1], origins[ray*3+1]);
    float pz = fmaf(t, dirs[ray*3+2], origins[ray*3+2]);
    int   b  = gidx[ray];

    float cx = ((px + 1.0f) * (float)GW - 1.0f) * 0.5f;
    float cy = ((py + 1.0f) * (float)GH - 1.0f) * 0.5f;
    float cz = ((pz + 1.0f) * (float)GD - 1.0f) * 0.5f;
    float fxf = floorf(cx), fyf = floorf(cy), fzf = floorf(cz);
    float fx = cx - fxf, fy = cy - fyf, fz = cz - fzf;
    int X = (int)fxf, Y = (int)fyf, Z = (int)fzf;

    // ---- trilinear gather (feat starts at ray encoding) ----
    float feat[C_IN];
    {
        const float4* e4 = (const float4*)(enc + (size_t)ray * C_IN);
        #pragma unroll
        for (int q = 0; q < C_IN/4; ++q) {
            float4 v = e4[q];
            feat[4*q+0] = v.x; feat[4*q+1] = v.y; feat[4*q+2] = v.z; feat[4*q+3] = v.w;
        }
    }
    int gx[2] = { clampi(X, GW-1), clampi(X+1, GW-1) };
    int gy[2] = { clampi(Y, GH-1), clampi(Y+1, GH-1) };
    int gz[2] = { clampi(Z, GD-1), clampi(Z+1, GD-1) };
    float wxa[2] = { 1.0f - fx, fx };
    float wya[2] = { 1.0f - fy, fy };
    float wza[2] = { 1.0f - fz, fz };
    #pragma unroll
    for (int dz = 0; dz < 2; ++dz)
    #pragma unroll
    for (int dy = 0; dy < 2; ++dy)
    #pragma unroll
    for (int dx = 0; dx < 2; ++dx) {
        float w = wza[dz] * wya[dy] * wxa[dx];
        size_t flat = ((((size_t)b * GD + gz[dz]) * GH + gy[dy]) * GW + gx[dx]) * C_IN;
        const float4* g4 = (const float4*)(grid + flat);
        #pragma unroll
        for (int q = 0; q < C_IN/4; ++q) {
            float4 v = g4[q];
            feat[4*q+0] = fmaf(w, v.x, feat[4*q+0]);
            feat[4*q+1] = fmaf(w, v.y, feat[4*q+1]);
            feat[4*q+2] = fmaf(w, v.z, feat[4*q+2]);
            feat[4*q+3] = fmaf(w, v.w, feat[4*q+3]);
        }
    }

    // ---- MLP (weights wave-uniform -> scalar loads) ----
    float h[C_HID];
    #pragma unroll
    for (int j = 0; j < C_HID; ++j) h[j] = b0[j];
    #pragma unroll
    for (int i = 0; i < C_IN; ++i) {
        float xi = feat[i];
        #pragma unroll
        for (int j = 0; j < C_HID; ++j) h[j] = fmaf(xi, W0[i*C_HID + j], h[j]);
    }
    #pragma unroll
    for (int j = 0; j < C_HID; ++j) h[j] = fmaxf(h[j], 0.0f);

    float o[C_OUT];
    #pragma unroll
    for (int j = 0; j < C_OUT; ++j) o[j] = b1[j];
    #pragma unroll
    for (int i = 0; i < C_HID; ++i) {
        float hi = h[i];
        #pragma unroll
        for (int j = 0; j < C_OUT; ++j) o[j] = fmaf(hi, W1[i*C_OUT + j], o[j]);
    }

    // ---- store point record (planar, coalesced) ----
    unsigned key = ((unsigned)(X + 256) & 511u)
                 | (((unsigned)(Y + 256) & 511u) << 9)
                 | (((unsigned)(Z + 256) & 511u) << 18);
    pf[pid] = make_float4(fx, fy, fz, __uint_as_float(key));
    #pragma unroll
    for (int q = 0; q < 4; ++q)
        po[(size_t)q * M_PTS + pid] = make_float4(o[4*q+0], o[4*q+1], o[4*q+2], o[4*q+3]);

    // ---- count touched tiles ----
    TileSpan ts = tile_span(X, Y, Z);
    #pragma unroll
    for (int ez = 0; ez < 2; ++ez) {
        if (ez && ts.tzb == ts.tza) continue;
        #pragma unroll
        for (int ey = 0; ey < 2; ++ey) {
            if (ey && ts.tyb == ts.tya) continue;
            #pragma unroll
            for (int ex = 0; ex < 2; ++ex) {
                if (ex && ts.txb == ts.txa) continue;
                int tt = ((ts.tza + ez) * TPA + (ts.tya + ey)) * TPA + (ts.txa + ex);
                atomicAdd(&lcnt[tt], 1u);
            }
        }
    }
    __syncthreads();
    for (int i = threadIdx.x; i < NTILES; i += 256)
        if (lcnt[i]) atomicAdd(&counts[i], lcnt[i]);
}

// ============================================================================
// K2: exclusive scan of 4096 tile counts (single block, simple & correct).
// ============================================================================
__global__ __launch_bounds__(256) void k2_scan(
    const unsigned* __restrict__ counts,
    unsigned* __restrict__ offsets, unsigned* __restrict__ alloc)
{
    __shared__ unsigned psum[256];
    int tid = threadIdx.x;
    unsigned base = tid * 16;
    unsigned ssum = 0;
    for (int i = 0; i < 16; ++i) ssum += counts[base + i];
    psum[tid] = ssum;
    __syncthreads();
    if (tid == 0) {
        unsigned r = 0;
        for (int i = 0; i < 256; ++i) { unsigned v = psum[i]; psum[i] = r; r += v; }
    }
    __syncthreads();
    unsigned run = psum[tid];
    for (int i = 0; i < 16; ++i) {
        unsigned v = counts[base + i];
        offsets[base + i] = run;
        alloc[base + i]   = run;
        run += v;
    }
}

// ============================================================================
// K3: scatter point indices into per-tile segments. Block-local LDS histogram
// + rank, one global atomicAdd per (block, nonzero tile) for segment alloc.
// ============================================================================
__global__ __launch_bounds__(256) void k3_scatter(
    const float4* __restrict__ pf, unsigned* __restrict__ alloc,
    unsigned* __restrict__ entries)
{
    __shared__ unsigned lcnt[NTILES];
    __shared__ unsigned lbase[NTILES];
    for (int i = threadIdx.x; i < NTILES; i += 256) lcnt[i] = 0;
    __syncthreads();

    int pid = blockIdx.x * 256 + threadIdx.x;
    float4 f = pf[pid];
    unsigned key = __float_as_uint(f.w);
    int X = (int)(key & 511u) - 256;
    int Y = (int)((key >> 9) & 511u) - 256;
    int Z = (int)((key >> 18) & 511u) - 256;
    TileSpan ts = tile_span(X, Y, Z);

    unsigned rnk[2][2][2];
    #pragma unroll
    for (int ez = 0; ez < 2; ++ez) {
        bool okz = (ez == 0) || (ts.tzb > ts.tza);
        #pragma unroll
        for (int ey = 0; ey < 2; ++ey) {
            bool oky = (ey == 0) || (ts.tyb > ts.tya);
            #pragma unroll
            for (int ex = 0; ex < 2; ++ex) {
                bool okx = (ex == 0) || (ts.txb > ts.txa);
                if (okz && oky && okx) {
                    int tt = ((ts.tza + ez) * TPA + (ts.tya + ey)) * TPA + (ts.txa + ex);
                    rnk[ez][ey][ex] = atomicAdd(&lcnt[tt], 1u);
                }
            }
        }
    }
    __syncthreads();
    for (int i = threadIdx.x; i < NTILES; i += 256)
        if (lcnt[i]) lbase[i] = atomicAdd(&alloc[i], lcnt[i]);
    __syncthreads();
    #pragma unroll
    for (int ez = 0; ez < 2; ++ez) {
        bool okz = (ez == 0) || (ts.tzb > ts.tza);
        #pragma unroll
        for (int ey = 0; ey < 2; ++ey) {
            bool oky = (ey == 0) || (ts.tyb > ts.tya);
            #pragma unroll
            for (int ex = 0; ex < 2; ++ex) {
                bool okx = (ex == 0) || (ts.txb > ts.txa);
                if (okz && oky && okx) {
                    int tt = ((ts.tza + ez) * TPA + (ts.tya + ey)) * TPA + (ts.txa + ex);
                    entries[lbase[tt] + rnk[ez][ey][ex]] = (unsigned)pid;
                }
            }
        }
    }
}

// ============================================================================
// K4 (REWRITTEN): NON-ATOMIC LDS read-modify-write accumulation.
// Race freedom by construction:
//  - wave w exclusively owns z-layers {2w, 2w+1} -> no cross-wave aliasing;
//  - lane = (corner dy,dx) x 16ch -> 64 distinct addresses per RMW instr
//    (2 lanes/bank = free); border-collapsed corners fold their weight into
//    the kept lane, duplicate lane redirected to a per-lane dummy slot;
//  - same-address across consecutive entries: LDS processes a wave's ds ops
//    in program order (compiler preserves order for unproven aliasing).
// Batched z-test (int4 read of 4 entries) gives cheap wave-uniform early-out.
// ============================================================================
__global__ __launch_bounds__(256) void k4_accum(
    const float4* __restrict__ pf, const float4* __restrict__ po,
    const unsigned* __restrict__ entries, const unsigned* __restrict__ offsets,
    const unsigned* __restrict__ alloc, float* __restrict__ out)
{
    __shared__ float  acc[TVOX*C_OUT + 64];  // [voxel][ch] + 64 dummy slots
    __shared__ float4 sA[CHUNK];             // fx, fy, fz, packed corner info
    __shared__ int    sZ[CHUNK];             // st0 | st1<<8 (z-layer idx or 255)
    __shared__ float  sOT[CHUNK * 17];       // o[16] transposed, stride 17

    int t  = blockIdx.x;
    int tx = t & (TPA-1), ty = (t >> 4) & (TPA-1), tz = t >> 8;
    int ox = tx * TW, oy = ty * TW, oz = tz * TW;

    int tid  = threadIdx.x;
    int lane = tid & 63;
    int w    = tid >> 6;            // wave id 0..3, owns z layers {2w, 2w+1}
    int ch   = lane & 15;
    int dx   = (lane >> 4) & 1;
    int dy   = (lane >> 5) & 1;
    int l0   = 2*w, l1 = 2*w + 1;

    for (int i = tid; i < TVOX*C_OUT + 64; i += 256) acc[i] = 0.0f;

    unsigned e0 = offsets[t], e1 = alloc[t];
    for (unsigned base = e0; base < e1; base += CHUNK) {
        int n = min((unsigned)CHUNK, e1 - base);
        if (tid < CHUNK) {
            if (tid < n) {
                unsigned p = entries[base + tid];
                float4 f = pf[p];
                unsigned key = __float_as_uint(f.w);
                int X = (int)(key & 511u) - 256;
                int Y = (int)((key >> 9) & 511u) - 256;
                int Z = (int)((key >> 18) & 511u) - 256;
                int cx0 = clampi(X, GW-1),  cx1 = clampi(X+1, GW-1);
                int cy0 = clampi(Y, GH-1),  cy1 = clampi(Y+1, GH-1);
                int cz0 = clampi(Z, GD-1),  cz1 = clampi(Z+1, GD-1);
                // 4-bit in-tile coords (8 = out-of-tile), collapse flags
                unsigned ex0 = ((unsigned)(cx0-ox) < 8u) ? (unsigned)(cx0-ox) : 8u;
                unsigned ex1 = ((unsigned)(cx1-ox) < 8u) ? (unsigned)(cx1-ox) : 8u;
                unsigned ey0 = ((unsigned)(cy0-oy) < 8u) ? (unsigned)(cy0-oy) : 8u;
                unsigned ey1 = ((unsigned)(cy1-oy) < 8u) ? (unsigned)(cy1-oy) : 8u;
                unsigned pk = ex0 | (ex1<<4) | (ey0<<8) | (ey1<<12)
                            | ((cx0==cx1) ? (1u<<16) : 0u)
                            | ((cy0==cy1) ? (1u<<17) : 0u);
                int st0 = ((unsigned)(cz0-oz) < 8u) ? (cz0-oz) : 255;
                int st1 = ((unsigned)(cz1-oz) < 8u) ? (cz1-oz) : 255;
                sA[tid] = make_float4(f.x, f.y, f.z, __uint_as_float(pk));
                sZ[tid] = st0 | (st1 << 8);
                #pragma unroll
                for (int q = 0; q < 4; ++q) {
                    float4 ov = po[(size_t)q * M_PTS + p];
                    sOT[tid*17 + 4*q+0] = ov.x;
                    sOT[tid*17 + 4*q+1] = ov.y;
                    sOT[tid*17 + 4*q+2] = ov.z;
                    sOT[tid*17 + 4*q+3] = ov.w;
                }
            } else {
                sZ[tid] = 255 | (255 << 8);   // sentinel: no wave hits
            }
        }
        __syncthreads();

        const int4* sZ4 = (const int4*)sZ;
        int n4 = (n + 3) & ~3;
        for (int jb = 0; jb < n4; jb += 4) {
            int4 z4 = sZ4[jb >> 2];
            #pragma unroll
            for (int k = 0; k < 4; ++k) {
                int zz  = (k==0) ? z4.x : (k==1) ? z4.y : (k==2) ? z4.z : z4.w;
                int st0 = zz & 255, st1 = (zz >> 8) & 255;
                bool hit = ((st0 >> 1) == w) | ((st1 >> 1) == w);
                if (!hit) continue;                  // wave-uniform skip
                int j = jb + k;
                float4 a = sA[j];
                unsigned pk = __float_as_uint(a.w);
                float oc = sOT[j*17 + ch];

                int  uxr  = (pk >> (dx << 2)) & 15;
                int  uyr  = (pk >> (8 + (dy << 2))) & 15;
                bool colx = (pk >> 16) & 1;
                bool coly = (pk >> 17) & 1;
                float wx = dx ? (colx ? 0.0f : a.x) : (colx ? 1.0f : 1.0f - a.x);
                float wy = dy ? (coly ? 0.0f : a.y) : (coly ? 1.0f : 1.0f - a.y);
                bool pred = (uxr < 8) & (uyr < 8)
                          & !(dx & (int)colx) & !(dy & (int)coly);
                float m = wx * wy * oc;
                int lxy = (uyr * TW + uxr) * C_OUT + ch;

                float wz0 = ((st0 == l0) ? (1.0f - a.z) : 0.0f)
                          + ((st1 == l0) ? a.z : 0.0f);
                if (wz0 != 0.0f) {                   // entry-uniform branch
                    int ad = pred ? (l0 * (TW*TW*C_OUT) + lxy) : (TVOX*C_OUT + lane);
                    acc[ad] += m * wz0;              // non-atomic LDS RMW
                }
                float wz1 = ((st0 == l1) ? (1.0f - a.z) : 0.0f)
                          + ((st1 == l1) ? a.z : 0.0f);
                if (wz1 != 0.0f) {
                    int ad = pred ? (l1 * (TW*TW*C_OUT) + lxy) : (TVOX*C_OUT + lane);
                    acc[ad] += m * wz1;
                }
            }
        }
        __syncthreads();
    }

    // ---- dense writeback: acc [voxel][ch] matches out layout directly ----
    for (int i = tid; i < (TVOX * C_OUT) / 4; i += 256) {
        int lin = i * 4;
        int c4  = lin & (C_OUT - 1);
        int v   = lin >> 4;
        int vx = v & (TW-1), vy = (v >> 3) & (TW-1), vz = v >> 6;
        size_t oaddr = ((((size_t)(oz + vz)) * GH + (oy + vy)) * GW + (ox + vx)) * C_OUT + c4;
        *(float4*)(out + oaddr) = *(const float4*)(acc + lin);
    }
}

// ============================================================================
// Fallback (round-3 fused kernel) if workspace is too small.
// ============================================================================
#define SEGS   8
#define SEGLEN (NSAMP / SEGS)
#define NTHREADS (N_RAYS * SEGS)

__global__ __launch_bounds__(256, 2) void splat_seg_kernel(
    const float* __restrict__ origins, const float* __restrict__ dirs,
    const float* __restrict__ nearv,   const float* __restrict__ farv,
    const float* __restrict__ enc,     const int*   __restrict__ gidx,
    const float* __restrict__ grid,    const float* __restrict__ W0,
    const float* __restrict__ b0,      const float* __restrict__ W1,
    const float* __restrict__ b1,      float* __restrict__ out)
{
    int tid = blockIdx.x * blockDim.x + threadIdx.x;
    if (tid >= NTHREADS) return;
    int ray = tid / SEGS;
    int seg = tid - ray * SEGS;
    float nr = nearv[ray], fr = farv[ray];
    float ox = origins[3*ray+0], oy = origins[3*ray+1], oz = origins[3*ray+2];
    float rdx = dirs[3*ray+0],   rdy = dirs[3*ray+1],   rdz = dirs[3*ray+2];
    int   b  = gidx[ray];
    float accv[8][C_OUT];
    #pragma unroll
    for (int sl = 0; sl < 8; ++sl)
        #pragma unroll
        for (int c = 0; c < C_OUT; ++c) accv[sl][c] = 0.0f;
    int Xp = 0, Yp = 0, Zp = 0;
    #pragma unroll 1
    for (int k = 0; k < SEGLEN; ++k) {
        int s = seg * SEGLEN + k;
        float t  = nr + (fr - nr) * ((float)s * (1.0f / (NSAMP - 1)));
        float px = fmaf(t, rdx, ox);
        float py = fmaf(t, rdy, oy);
        float pz = fmaf(t, rdz, oz);
        float cx = ((px + 1.0f) * (float)GW - 1.0f) * 0.5f;
        float cy = ((py + 1.0f) * (float)GH - 1.0f) * 0.5f;
        float cz = ((pz + 1.0f) * (float)GD - 1.0f) * 0.5f;
        float fxf = floorf(cx), fyf = floorf(cy), fzf = floorf(cz);
        float fx = cx - fxf, fy = cy - fyf, fz = cz - fzf;
        int X = (int)fxf, Y = (int)fyf, Z = (int)fzf;
        if (k == 0) { Xp = X; Yp = Y; Zp = Z; }
        else if (X != Xp || Y != Yp || Z != Zp) {
            bool fXm[2], fYm[2], fZm[2];
            int  vx[2], vy[2], vz[2];
            #pragma unroll
            for (int p = 0; p < 2; ++p) {
                int xo = Xp + ((Xp ^ p) & 1), xn = X + ((X ^ p) & 1);
                fXm[p] = (xo != xn);  vx[p] = clampi(xo, GW-1);
                int yo = Yp + ((Yp ^ p) & 1), yn = Y + ((Y ^ p) & 1);
                fYm[p] = (yo != yn);  vy[p] = clampi(yo, GH-1);
                int zo = Zp + ((Zp ^ p) & 1), zn = Z + ((Z ^ p) & 1);
                fZm[p] = (zo != zn);  vz[p] = clampi(zo, GD-1);
            }
            #pragma unroll
            for (int pxi = 0; pxi < 2; ++pxi)
            #pragma unroll
            for (int pyi = 0; pyi < 2; ++pyi)
            #pragma unroll
            for (int pzi = 0; pzi < 2; ++pzi) {
                const int sl = pxi*4 + pyi*2 + pzi;
                if (fXm[pxi] | fYm[pyi] | fZm[pzi]) {
                    size_t flat = ((((size_t)b * GD + vz[pzi]) * GH + vy[pyi]) * GW + vx[pxi]) * C_OUT;
                    float* op = out + flat;
                    #pragma unroll
                    for (int c = 0; c < C_OUT; ++c) { atomicAdd(op + c, accv[sl][c]); accv[sl][c] = 0.0f; }
                }
            }
            Xp = X; Yp = Y; Zp = Z;
        }
        float feat[C_IN];
        {
            const float4* e4 = (const float4*)(enc + (size_t)ray * C_IN);
            #pragma unroll
            for (int q = 0; q < C_IN/4; ++q) {
                float4 v = e4[q];
                feat[4*q+0] = v.x; feat[4*q+1] = v.y; feat[4*q+2] = v.z; feat[4*q+3] = v.w;
            }
        }
        int gx[2] = { clampi(X, GW-1), clampi(X+1, GW-1) };
        int gy[2] = { clampi(Y, GH-1), clampi(Y+1, GH-1) };
        int gz[2] = { clampi(Z, GD-1), clampi(Z+1, GD-1) };
        float wxa[2] = { 1.0f - fx, fx };
        float wya[2] = { 1.0f - fy, fy };
        float wza[2] = { 1.0f - fz, fz };
        #pragma unroll
        for (int dz = 0; dz < 2; ++dz)
        #pragma unroll
        for (int dy = 0; dy < 2; ++dy)
        #pragma unroll
        for (int dx = 0; dx < 2; ++dx) {
            float w = wza[dz] * wya[dy] * wxa[dx];
            size_t flat = ((((size_t)b * GD + gz[dz]) * GH + gy[dy]) * GW + gx[dx]) * C_IN;
            const float4* g4 = (const float4*)(grid + flat);
            #pragma unroll
            for (int q = 0; q < C_IN/4; ++q) {
                float4 v = g4[q];
                feat[4*q+0] = fmaf(w, v.x, feat[4*q+0]);
                feat[4*q+1] = fmaf(w, v.y, feat[4*q+1]);
                feat[4*q+2] = fmaf(w, v.z, feat[4*q+2]);
                feat[4*q+3] = fmaf(w, v.w, feat[4*q+3]);
            }
        }
        float h[C_HID];
        #pragma unroll
        for (int j = 0; j < C_HID; ++j) h[j] = b0[j];
        #pragma unroll
        for (int i = 0; i < C_IN; ++i) {
            float xi = feat[i];
            #pragma unroll
            for (int j = 0; j < C_HID; ++j) h[j] = fmaf(xi, W0[i*C_HID + j], h[j]);
        }
        #pragma unroll
        for (int j = 0; j < C_HID; ++j) h[j] = fmaxf(h[j], 0.0f);
        float o[C_OUT];
        #pragma unroll
        for (int j = 0; j < C_OUT; ++j) o[j] = b1[j];
        #pragma unroll
        for (int i = 0; i < C_HID; ++i) {
            float hi = h[i];
            #pragma unroll
            for (int j = 0; j < C_OUT; ++j) o[j] = fmaf(hi, W1[i*C_OUT + j], o[j]);
        }
        float wxs[2], wys[2], wzs[2];
        #pragma unroll
        for (int p = 0; p < 2; ++p) {
            wxs[p] = ((X & 1) == p) ? (1.0f - fx) : fx;
            wys[p] = ((Y & 1) == p) ? (1.0f - fy) : fy;
            wzs[p] = ((Z & 1) == p) ? (1.0f - fz) : fz;
        }
        #pragma unroll
        for (int pxi = 0; pxi < 2; ++pxi)
        #pragma unroll
        for (int pyi = 0; pyi < 2; ++pyi)
        #pragma unroll
        for (int pzi = 0; pzi < 2; ++pzi) {
            const int sl = pxi*4 + pyi*2 + pzi;
            float w = wxs[pxi] * wys[pyi] * wzs[pzi];
            #pragma unroll
            for (int c = 0; c < C_OUT; ++c) accv[sl][c] = fmaf(w, o[c], accv[sl][c]);
        }
    }
    #pragma unroll
    for (int pxi = 0; pxi < 2; ++pxi)
    #pragma unroll
    for (int pyi = 0; pyi < 2; ++pyi)
    #pragma unroll
    for (int pzi = 0; pzi < 2; ++pzi) {
        const int sl = pxi*4 + pyi*2 + pzi;
        int vx = clampi(Xp + ((Xp ^ pxi) & 1), GW-1);
        int vy = clampi(Yp + ((Yp ^ pyi) & 1), GH-1);
        int vz = clampi(Zp + ((Zp ^ pzi) & 1), GD-1);
        size_t flat = ((((size_t)b * GD + vz) * GH + vy) * GW + vx) * C_OUT;
        float* op = out + flat;
        #pragma unroll
        for (int c = 0; c < C_OUT; ++c) atomicAdd(op + c, accv[sl][c]);
    }
}

// ============================================================================
extern "C" void kernel_launch(void* const* d_in, const int* in_sizes, int n_in,
                              void* d_out, int out_size, void* d_ws, size_t ws_size,
                              hipStream_t stream) {
    const float* origins = (const float*)d_in[0];
    const float* dirs    = (const float*)d_in[1];
    const float* nearv   = (const float*)d_in[2];
    const float* farv    = (const float*)d_in[3];
    const float* enc     = (const float*)d_in[4];
    const int*   gidx    = (const int*)  d_in[5];
    const float* grid    = (const float*)d_in[6];
    const float* W0      = (const float*)d_in[7];
    const float* b0      = (const float*)d_in[8];
    const float* W1      = (const float*)d_in[9];
    const float* b1      = (const float*)d_in[10];
    float* out = (float*)d_out;

    const size_t PF_B = (size_t)M_PTS * 16;         // 25,165,824
    const size_t PO_B = (size_t)M_PTS * 64;         // 100,663,296
    const size_t EN_B = (size_t)M_PTS * 8 * 4;      // 50,331,648 (hard bound)
    const size_t CT_B = (size_t)NTILES * 4;
    const size_t NEED = PF_B + PO_B + EN_B + 3 * CT_B;

    if (ws_size < NEED) {
        // fallback: fused register-merged scatter (round-3 path)
        hipMemsetAsync(out, 0, (size_t)out_size * sizeof(float), stream);
        splat_seg_kernel<<<NTHREADS/256, 256, 0, stream>>>(
            origins, dirs, nearv, farv, enc, gidx, grid, W0, b0, W1, b1, out);
        return;
    }

    char* w = (char*)d_ws;
    float4*   pf      = (float4*)   w;              w += PF_B;
    float4*   po      = (float4*)   w;              w += PO_B;
    unsigned* entries = (unsigned*) w;              w += EN_B;
    unsigned* counts  = (unsigned*) w;              w += CT_B;
    unsigned* offsets = (unsigned*) w;              w += CT_B;
    unsigned* alloc   = (unsigned*) w;              w += CT_B;

    hipMemsetAsync(counts, 0, CT_B, stream);
    k1_point<<<M_PTS/256, 256, 0, stream>>>(origins, dirs, nearv, farv, enc, gidx,
                                            grid, W0, b0, W1, b1, pf, po, counts);
    k2_scan<<<1, 256, 0, stream>>>(counts, offsets, alloc);
    k3_scatter<<<M_PTS/256, 256, 0, stream>>>(pf, alloc, entries);
    k4_accum<<<NTILES, 256, 0, stream>>>(pf, po, entries, offsets, alloc, out);
    // K4 writes every output voxel densely -> no output memset needed.
}

// Round 9
// 885.441 us; speedup vs baseline: 2.2389x; 1.3251x over previous
//
#include <hip/hip_runtime.h>

#define N_RAYS 16384
#define NSAMP  96
#define GD 128
#define GH 128
#define GW 128
#define C_IN  32
#define C_HID 32
#define C_OUT 16
#define M_PTS (N_RAYS * NSAMP)       // 1,572,864 (divisible by 256)
#define TPA 16                        // tiles per axis (128/8)
#define NTILES (TPA*TPA*TPA)          // 4096
#define TW 8                          // tile width (voxels)
#define TVOX (TW*TW*TW)               // 512 voxels per tile
#define CHUNK 128                     // entries staged per K4 inner pass

__device__ __forceinline__ int clampi(int v, int hi) { return min(max(v, 0), hi); }

struct TileSpan { int txa, txb, tya, tyb, tza, tzb; };
__device__ __forceinline__ TileSpan tile_span(int X, int Y, int Z) {
    TileSpan s;
    s.txa = clampi(X,   GW-1) >> 3;  s.txb = clampi(X+1, GW-1) >> 3;
    s.tya = clampi(Y,   GH-1) >> 3;  s.tyb = clampi(Y+1, GH-1) >> 3;
    s.tza = clampi(Z,   GD-1) >> 3;  s.tzb = clampi(Z+1, GD-1) >> 3;
    return s;
}

// ============================================================================
// K1: per-point gather + MLP. Stores o[16] (planar float4) + frac/key, and
// accumulates per-tile point counts (LDS histogram -> global atomicAdd).
// ============================================================================
__global__ __launch_bounds__(256) void k1_point(
    const float* __restrict__ origins, const float* __restrict__ dirs,
    const float* __restrict__ nearv,   const float* __restrict__ farv,
    const float* __restrict__ enc,     const int*   __restrict__ gidx,
    const float* __restrict__ grid,    const float* __restrict__ W0,
    const float* __restrict__ b0,      const float* __restrict__ W1,
    const float* __restrict__ b1,
    float4* __restrict__ pf, float4* __restrict__ po, unsigned* __restrict__ counts)
{
    __shared__ unsigned lcnt[NTILES];
    for (int i = threadIdx.x; i < NTILES; i += 256) lcnt[i] = 0;
    __syncthreads();

    int pid = blockIdx.x * 256 + threadIdx.x;     // always < M_PTS (exact grid)
    int ray = pid / NSAMP;
    int s   = pid - ray * NSAMP;

    float nr = nearv[ray], fr = farv[ray];
    float t  = nr + (fr - nr) * ((float)s * (1.0f / (NSAMP - 1)));
    float px = fmaf(t, dirs[ray*3+0], origins[ray*3+0]);
    float py = fmaf(t, dirs[ray*3+1], origins[ray*3+1]);
    float pz = fmaf(t, dirs[ray*3+2], origins[ray*3+2]);
    int   b  = gidx[ray];

    float cx = ((px + 1.0f) * (float)GW - 1.0f) * 0.5f;
    float cy = ((py + 1.0f) * (float)GH - 1.0f) * 0.5f;
    float cz = ((pz + 1.0f) * (float)GD - 1.0f) * 0.5f;
    float fxf = floorf(cx), fyf = floorf(cy), fzf = floorf(cz);
    float fx = cx - fxf, fy = cy - fyf, fz = cz - fzf;
    int X = (int)fxf, Y = (int)fyf, Z = (int)fzf;

    // ---- trilinear gather (feat starts at ray encoding) ----
    float feat[C_IN];
    {
        const float4* e4 = (const float4*)(enc + (size_t)ray * C_IN);
        #pragma unroll
        for (int q = 0; q < C_IN/4; ++q) {
            float4 v = e4[q];
            feat[4*q+0] = v.x; feat[4*q+1] = v.y; feat[4*q+2] = v.z; feat[4*q+3] = v.w;
        }
    }
    int gx[2] = { clampi(X, GW-1), clampi(X+1, GW-1) };
    int gy[2] = { clampi(Y, GH-1), clampi(Y+1, GH-1) };
    int gz[2] = { clampi(Z, GD-1), clampi(Z+1, GD-1) };
    float wxa[2] = { 1.0f - fx, fx };
    float wya[2] = { 1.0f - fy, fy };
    float wza[2] = { 1.0f - fz, fz };
    #pragma unroll
    for (int dz = 0; dz < 2; ++dz)
    #pragma unroll
    for (int dy = 0; dy < 2; ++dy)
    #pragma unroll
    for (int dx = 0; dx < 2; ++dx) {
        float w = wza[dz] * wya[dy] * wxa[dx];
        size_t flat = ((((size_t)b * GD + gz[dz]) * GH + gy[dy]) * GW + gx[dx]) * C_IN;
        const float4* g4 = (const float4*)(grid + flat);
        #pragma unroll
        for (int q = 0; q < C_IN/4; ++q) {
            float4 v = g4[q];
            feat[4*q+0] = fmaf(w, v.x, feat[4*q+0]);
            feat[4*q+1] = fmaf(w, v.y, feat[4*q+1]);
            feat[4*q+2] = fmaf(w, v.z, feat[4*q+2]);
            feat[4*q+3] = fmaf(w, v.w, feat[4*q+3]);
        }
    }

    // ---- MLP (weights wave-uniform -> scalar loads) ----
    float h[C_HID];
    #pragma unroll
    for (int j = 0; j < C_HID; ++j) h[j] = b0[j];
    #pragma unroll
    for (int i = 0; i < C_IN; ++i) {
        float xi = feat[i];
        #pragma unroll
        for (int j = 0; j < C_HID; ++j) h[j] = fmaf(xi, W0[i*C_HID + j], h[j]);
    }
    #pragma unroll
    for (int j = 0; j < C_HID; ++j) h[j] = fmaxf(h[j], 0.0f);

    float o[C_OUT];
    #pragma unroll
    for (int j = 0; j < C_OUT; ++j) o[j] = b1[j];
    #pragma unroll
    for (int i = 0; i < C_HID; ++i) {
        float hi = h[i];
        #pragma unroll
        for (int j = 0; j < C_OUT; ++j) o[j] = fmaf(hi, W1[i*C_OUT + j], o[j]);
    }

    // ---- store point record (planar, coalesced) ----
    unsigned key = ((unsigned)(X + 256) & 511u)
                 | (((unsigned)(Y + 256) & 511u) << 9)
                 | (((unsigned)(Z + 256) & 511u) << 18);
    pf[pid] = make_float4(fx, fy, fz, __uint_as_float(key));
    #pragma unroll
    for (int q = 0; q < 4; ++q)
        po[(size_t)q * M_PTS + pid] = make_float4(o[4*q+0], o[4*q+1], o[4*q+2], o[4*q+3]);

    // ---- count touched tiles ----
    TileSpan ts = tile_span(X, Y, Z);
    #pragma unroll
    for (int ez = 0; ez < 2; ++ez) {
        if (ez && ts.tzb == ts.tza) continue;
        #pragma unroll
        for (int ey = 0; ey < 2; ++ey) {
            if (ey && ts.tyb == ts.tya) continue;
            #pragma unroll
            for (int ex = 0; ex < 2; ++ex) {
                if (ex && ts.txb == ts.txa) continue;
                int tt = ((ts.tza + ez) * TPA + (ts.tya + ey)) * TPA + (ts.txa + ex);
                atomicAdd(&lcnt[tt], 1u);
            }
        }
    }
    __syncthreads();
    for (int i = threadIdx.x; i < NTILES; i += 256)
        if (lcnt[i]) atomicAdd(&counts[i], lcnt[i]);
}

// ============================================================================
// K2: exclusive scan of 4096 tile counts (single block, simple & correct).
// ============================================================================
__global__ __launch_bounds__(256) void k2_scan(
    const unsigned* __restrict__ counts,
    unsigned* __restrict__ offsets, unsigned* __restrict__ alloc)
{
    __shared__ unsigned psum[256];
    int tid = threadIdx.x;
    unsigned base = tid * 16;
    unsigned ssum = 0;
    for (int i = 0; i < 16; ++i) ssum += counts[base + i];
    psum[tid] = ssum;
    __syncthreads();
    if (tid == 0) {
        unsigned r = 0;
        for (int i = 0; i < 256; ++i) { unsigned v = psum[i]; psum[i] = r; r += v; }
    }
    __syncthreads();
    unsigned run = psum[tid];
    for (int i = 0; i < 16; ++i) {
        unsigned v = counts[base + i];
        offsets[base + i] = run;
        alloc[base + i]   = run;
        run += v;
    }
}

// ============================================================================
// K3: scatter point indices into per-tile segments. Block-local LDS histogram
// + rank, one global atomicAdd per (block, nonzero tile) for segment alloc.
// ============================================================================
__global__ __launch_bounds__(256) void k3_scatter(
    const float4* __restrict__ pf, unsigned* __restrict__ alloc,
    unsigned* __restrict__ entries)
{
    __shared__ unsigned lcnt[NTILES];
    __shared__ unsigned lbase[NTILES];
    for (int i = threadIdx.x; i < NTILES; i += 256) lcnt[i] = 0;
    __syncthreads();

    int pid = blockIdx.x * 256 + threadIdx.x;
    float4 f = pf[pid];
    unsigned key = __float_as_uint(f.w);
    int X = (int)(key & 511u) - 256;
    int Y = (int)((key >> 9) & 511u) - 256;
    int Z = (int)((key >> 18) & 511u) - 256;
    TileSpan ts = tile_span(X, Y, Z);

    unsigned rnk[2][2][2];
    #pragma unroll
    for (int ez = 0; ez < 2; ++ez) {
        bool okz = (ez == 0) || (ts.tzb > ts.tza);
        #pragma unroll
        for (int ey = 0; ey < 2; ++ey) {
            bool oky = (ey == 0) || (ts.tyb > ts.tya);
            #pragma unroll
            for (int ex = 0; ex < 2; ++ex) {
                bool okx = (ex == 0) || (ts.txb > ts.txa);
                if (okz && oky && okx) {
                    int tt = ((ts.tza + ez) * TPA + (ts.tya + ey)) * TPA + (ts.txa + ex);
                    rnk[ez][ey][ex] = atomicAdd(&lcnt[tt], 1u);
                }
            }
        }
    }
    __syncthreads();
    for (int i = threadIdx.x; i < NTILES; i += 256)
        if (lcnt[i]) lbase[i] = atomicAdd(&alloc[i], lcnt[i]);
    __syncthreads();
    #pragma unroll
    for (int ez = 0; ez < 2; ++ez) {
        bool okz = (ez == 0) || (ts.tzb > ts.tza);
        #pragma unroll
        for (int ey = 0; ey < 2; ++ey) {
            bool oky = (ey == 0) || (ts.tyb > ts.tya);
            #pragma unroll
            for (int ex = 0; ex < 2; ++ex) {
                bool okx = (ex == 0) || (ts.txb > ts.txa);
                if (okz && oky && okx) {
                    int tt = ((ts.tza + ez) * TPA + (ts.tya + ey)) * TPA + (ts.txa + ex);
                    entries[lbase[tt] + rnk[ez][ey][ex]] = (unsigned)pid;
                }
            }
        }
    }
}

// ============================================================================
// K4 (HYBRID r6+r8): register accumulation + batched wave-uniform z skip.
// Wave w owns z-layers {2w, 2w+1}; lane owns (x,y) = (lane&7, lane>>3) at
// both layers -> 2x16 fp32 accumulators in REGISTERS (no LDS on the accumulate
// path, no RMW chains, no atomics). Per entry on a hit wave: broadcast sA +
// 4x b128 sO broadcasts + unconditional 32 FMAs (miss lanes get weight 0;
// '==' against both clamped corners folds border-collapse weights, as in r6).
// Non-hit waves skip entries via the int4-batched sZ scan (r8's trick).
// Dense float4 writeback replaces the output memset.
// ============================================================================
__global__ __launch_bounds__(256) void k4_accum(
    const float4* __restrict__ pf, const float4* __restrict__ po,
    const unsigned* __restrict__ entries, const unsigned* __restrict__ offsets,
    const unsigned* __restrict__ alloc, float* __restrict__ out)
{
    __shared__ __attribute__((aligned(16))) float4 sA[CHUNK]; // fx,fy,fz, cx0|cx1|cy0|cy1
    __shared__ __attribute__((aligned(16))) int    sZ[CHUNK]; // st0|st1<<8 (255=out)
    __shared__ __attribute__((aligned(16))) float4 sO[4*CHUNK]; // o[16] planar [q][entry]

    int t  = blockIdx.x;
    int tx = t & (TPA-1), ty = (t >> 4) & (TPA-1), tz = t >> 8;
    int ox = tx * TW, oy = ty * TW, oz = tz * TW;

    int tid  = threadIdx.x;
    int lane = tid & 63;
    int w    = tid >> 6;             // wave id, owns z-layers {2w, 2w+1}
    int vxa  = ox + (lane & 7);      // absolute voxel coords this lane owns
    int vya  = oy + (lane >> 3);
    int l0   = 2*w, l1 = 2*w + 1;    // tile-relative z layers

    float accA[C_OUT], accB[C_OUT];
    #pragma unroll
    for (int c = 0; c < C_OUT; ++c) { accA[c] = 0.0f; accB[c] = 0.0f; }

    unsigned e0 = offsets[t], e1 = alloc[t];
    for (unsigned base = e0; base < e1; base += CHUNK) {
        int n = min((unsigned)CHUNK, e1 - base);
        if (tid < CHUNK) {
            if (tid < n) {
                unsigned p = entries[base + tid];
                float4 f = pf[p];
                unsigned key = __float_as_uint(f.w);
                int X = (int)(key & 511u) - 256;
                int Y = (int)((key >> 9) & 511u) - 256;
                int Z = (int)((key >> 18) & 511u) - 256;
                int cx0 = clampi(X, GW-1),  cx1 = clampi(X+1, GW-1);
                int cy0 = clampi(Y, GH-1),  cy1 = clampi(Y+1, GH-1);
                int cz0 = clampi(Z, GD-1),  cz1 = clampi(Z+1, GD-1);
                unsigned pk = (unsigned)cx0 | ((unsigned)cx1 << 8)
                            | ((unsigned)cy0 << 16) | ((unsigned)cy1 << 24);
                int st0 = ((unsigned)(cz0 - oz) < 8u) ? (cz0 - oz) : 255;
                int st1 = ((unsigned)(cz1 - oz) < 8u) ? (cz1 - oz) : 255;
                sA[tid] = make_float4(f.x, f.y, f.z, __uint_as_float(pk));
                sZ[tid] = st0 | (st1 << 8);
                #pragma unroll
                for (int q = 0; q < 4; ++q)
                    sO[q*CHUNK + tid] = po[(size_t)q * M_PTS + p];
            } else {
                sZ[tid] = 255 | (255 << 8);   // sentinel: hits no wave
            }
        }
        __syncthreads();

        const int4* sZ4 = (const int4*)sZ;
        int n4 = (n + 3) & ~3;
        for (int jb = 0; jb < n4; jb += 4) {
            int4 z4 = sZ4[jb >> 2];                     // broadcast batch of 4
            #pragma unroll
            for (int k = 0; k < 4; ++k) {
                int zz  = (k==0) ? z4.x : (k==1) ? z4.y : (k==2) ? z4.z : z4.w;
                int st0 = zz & 255, st1 = (zz >> 8) & 255;
                if (((st0 >> 1) != w) & ((st1 >> 1) != w)) continue; // uniform skip
                int j = jb + k;
                float4 a = sA[j];                        // b128 broadcast
                unsigned pk = __float_as_uint(a.w);
                int cx0 = (int)(pk & 255u),         cx1 = (int)((pk >> 8) & 255u);
                int cy0 = (int)((pk >> 16) & 255u), cy1 = (int)(pk >> 24);

                // '==' both corners: collapse at borders sums both weights
                float wx = ((vxa == cx0) ? 1.0f - a.x : 0.0f)
                         + ((vxa == cx1) ? a.x        : 0.0f);
                float wy = ((vya == cy0) ? 1.0f - a.y : 0.0f)
                         + ((vya == cy1) ? a.y        : 0.0f);
                float wzA = ((st0 == l0) ? 1.0f - a.z : 0.0f)
                          + ((st1 == l0) ? a.z        : 0.0f);
                float wzB = ((st0 == l1) ? 1.0f - a.z : 0.0f)
                          + ((st1 == l1) ? a.z        : 0.0f);
                float wxy = wx * wy;
                float wA = wxy * wzA, wB = wxy * wzB;    // 0 on miss lanes

                #pragma unroll
                for (int q = 0; q < 4; ++q) {
                    float4 ov = sO[q*CHUNK + j];         // b128 broadcast
                    accA[4*q+0] = fmaf(wA, ov.x, accA[4*q+0]);
                    accA[4*q+1] = fmaf(wA, ov.y, accA[4*q+1]);
                    accA[4*q+2] = fmaf(wA, ov.z, accA[4*q+2]);
                    accA[4*q+3] = fmaf(wA, ov.w, accA[4*q+3]);
                    accB[4*q+0] = fmaf(wB, ov.x, accB[4*q+0]);
                    accB[4*q+1] = fmaf(wB, ov.y, accB[4*q+1]);
                    accB[4*q+2] = fmaf(wB, ov.z, accB[4*q+2]);
                    accB[4*q+3] = fmaf(wB, ov.w, accB[4*q+3]);
                }
            }
        }
        __syncthreads();
    }

    // ---- dense register writeback (full coverage -> no memset needed) ----
    size_t baseA = ((((size_t)(oz + l0)) * GH + vya) * GW + vxa) * C_OUT;
    size_t baseB = ((((size_t)(oz + l1)) * GH + vya) * GW + vxa) * C_OUT;
    #pragma unroll
    for (int q = 0; q < 4; ++q) {
        *(float4*)(out + baseA + 4*q) = make_float4(accA[4*q+0], accA[4*q+1], accA[4*q+2], accA[4*q+3]);
        *(float4*)(out + baseB + 4*q) = make_float4(accB[4*q+0], accB[4*q+1], accB[4*q+2], accB[4*q+3]);
    }
}

// ============================================================================
// Fallback (round-3 fused kernel) if workspace is too small.
// ============================================================================
#define SEGS   8
#define SEGLEN (NSAMP / SEGS)
#define NTHREADS (N_RAYS * SEGS)

__global__ __launch_bounds__(256, 2) void splat_seg_kernel(
    const float* __restrict__ origins, const float* __restrict__ dirs,
    const float* __restrict__ nearv,   const float* __restrict__ farv,
    const float* __restrict__ enc,     const int*   __restrict__ gidx,
    const float* __restrict__ grid,    const float* __restrict__ W0,
    const float* __restrict__ b0,      const float* __restrict__ W1,
    const float* __restrict__ b1,      float* __restrict__ out)
{
    int tid = blockIdx.x * blockDim.x + threadIdx.x;
    if (tid >= NTHREADS) return;
    int ray = tid / SEGS;
    int seg = tid - ray * SEGS;
    float nr = nearv[ray], fr = farv[ray];
    float ox = origins[3*ray+0], oy = origins[3*ray+1], oz = origins[3*ray+2];
    float rdx = dirs[3*ray+0],   rdy = dirs[3*ray+1],   rdz = dirs[3*ray+2];
    int   b  = gidx[ray];
    float accv[8][C_OUT];
    #pragma unroll
    for (int sl = 0; sl < 8; ++sl)
        #pragma unroll
        for (int c = 0; c < C_OUT; ++c) accv[sl][c] = 0.0f;
    int Xp = 0, Yp = 0, Zp = 0;
    #pragma unroll 1
    for (int k = 0; k < SEGLEN; ++k) {
        int s = seg * SEGLEN + k;
        float t  = nr + (fr - nr) * ((float)s * (1.0f / (NSAMP - 1)));
        float px = fmaf(t, rdx, ox);
        float py = fmaf(t, rdy, oy);
        float pz = fmaf(t, rdz, oz);
        float cx = ((px + 1.0f) * (float)GW - 1.0f) * 0.5f;
        float cy = ((py + 1.0f) * (float)GH - 1.0f) * 0.5f;
        float cz = ((pz + 1.0f) * (float)GD - 1.0f) * 0.5f;
        float fxf = floorf(cx), fyf = floorf(cy), fzf = floorf(cz);
        float fx = cx - fxf, fy = cy - fyf, fz = cz - fzf;
        int X = (int)fxf, Y = (int)fyf, Z = (int)fzf;
        if (k == 0) { Xp = X; Yp = Y; Zp = Z; }
        else if (X != Xp || Y != Yp || Z != Zp) {
            bool fXm[2], fYm[2], fZm[2];
            int  vx[2], vy[2], vz[2];
            #pragma unroll
            for (int p = 0; p < 2; ++p) {
                int xo = Xp + ((Xp ^ p) & 1), xn = X + ((X ^ p) & 1);
                fXm[p] = (xo != xn);  vx[p] = clampi(xo, GW-1);
                int yo = Yp + ((Yp ^ p) & 1), yn = Y + ((Y ^ p) & 1);
                fYm[p] = (yo != yn);  vy[p] = clampi(yo, GH-1);
                int zo = Zp + ((Zp ^ p) & 1), zn = Z + ((Z ^ p) & 1);
                fZm[p] = (zo != zn);  vz[p] = clampi(zo, GD-1);
            }
            #pragma unroll
            for (int pxi = 0; pxi < 2; ++pxi)
            #pragma unroll
            for (int pyi = 0; pyi < 2; ++pyi)
            #pragma unroll
            for (int pzi = 0; pzi < 2; ++pzi) {
                const int sl = pxi*4 + pyi*2 + pzi;
                if (fXm[pxi] | fYm[pyi] | fZm[pzi]) {
                    size_t flat = ((((size_t)b * GD + vz[pzi]) * GH + vy[pyi]) * GW + vx[pxi]) * C_OUT;
                    float* op = out + flat;
                    #pragma unroll
                    for (int c = 0; c < C_OUT; ++c) { atomicAdd(op + c, accv[sl][c]); accv[sl][c] = 0.0f; }
                }
            }
            Xp = X; Yp = Y; Zp = Z;
        }
        float feat[C_IN];
        {
            const float4* e4 = (const float4*)(enc + (size_t)ray * C_IN);
            #pragma unroll
            for (int q = 0; q < C_IN/4; ++q) {
                float4 v = e4[q];
                feat[4*q+0] = v.x; feat[4*q+1] = v.y; feat[4*q+2] = v.z; feat[4*q+3] = v.w;
            }
        }
        int gx[2] = { clampi(X, GW-1), clampi(X+1, GW-1) };
        int gy[2] = { clampi(Y, GH-1), clampi(Y+1, GH-1) };
        int gz[2] = { clampi(Z, GD-1), clampi(Z+1, GD-1) };
        float wxa[2] = { 1.0f - fx, fx };
        float wya[2] = { 1.0f - fy, fy };
        float wza[2] = { 1.0f - fz, fz };
        #pragma unroll
        for (int dz = 0; dz < 2; ++dz)
        #pragma unroll
        for (int dy = 0; dy < 2; ++dy)
        #pragma unroll
        for (int dx = 0; dx < 2; ++dx) {
            float w = wza[dz] * wya[dy] * wxa[dx];
            size_t flat = ((((size_t)b * GD + gz[dz]) * GH + gy[dy]) * GW + gx[dx]) * C_IN;
            const float4* g4 = (const float4*)(grid + flat);
            #pragma unroll
            for (int q = 0; q < C_IN/4; ++q) {
                float4 v = g4[q];
                feat[4*q+0] = fmaf(w, v.x, feat[4*q+0]);
                feat[4*q+1] = fmaf(w, v.y, feat[4*q+1]);
                feat[4*q+2] = fmaf(w, v.z, feat[4*q+2]);
                feat[4*q+3] = fmaf(w, v.w, feat[4*q+3]);
            }
        }
        float h[C_HID];
        #pragma unroll
        for (int j = 0; j < C_HID; ++j) h[j] = b0[j];
        #pragma unroll
        for (int i = 0; i < C_IN; ++i) {
            float xi = feat[i];
            #pragma unroll
            for (int j = 0; j < C_HID; ++j) h[j] = fmaf(xi, W0[i*C_HID + j], h[j]);
        }
        #pragma unroll
        for (int j = 0; j < C_HID; ++j) h[j] = fmaxf(h[j], 0.0f);
        float o[C_OUT];
        #pragma unroll
        for (int j = 0; j < C_OUT; ++j) o[j] = b1[j];
        #pragma unroll
        for (int i = 0; i < C_HID; ++i) {
            float hi = h[i];
            #pragma unroll
            for (int j = 0; j < C_OUT; ++j) o[j] = fmaf(hi, W1[i*C_OUT + j], o[j]);
        }
        float wxs[2], wys[2], wzs[2];
        #pragma unroll
        for (int p = 0; p < 2; ++p) {
            wxs[p] = ((X & 1) == p) ? (1.0f - fx) : fx;
            wys[p] = ((Y & 1) == p) ? (1.0f - fy) : fy;
            wzs[p] = ((Z & 1) == p) ? (1.0f - fz) : fz;
        }
        #pragma unroll
        for (int pxi = 0; pxi < 2; ++pxi)
        #pragma unroll
        for (int pyi = 0; pyi < 2; ++pyi)
        #pragma unroll
        for (int pzi = 0; pzi < 2; ++pzi) {
            const int sl = pxi*4 + pyi*2 + pzi;
            float w = wxs[pxi] * wys[pyi] * wzs[pzi];
            #pragma unroll
            for (int c = 0; c < C_OUT; ++c) accv[sl][c] = fmaf(w, o[c], accv[sl][c]);
        }
    }
    #pragma unroll
    for (int pxi = 0; pxi < 2; ++pxi)
    #pragma unroll
    for (int pyi = 0; pyi < 2; ++pyi)
    #pragma unroll
    for (int pzi = 0; pzi < 2; ++pzi) {
        const int sl = pxi*4 + pyi*2 + pzi;
        int vx = clampi(Xp + ((Xp ^ pxi) & 1), GW-1);
        int vy = clampi(Yp + ((Yp ^ pyi) & 1), GH-1);
        int vz = clampi(Zp + ((Zp ^ pzi) & 1), GD-1);
        size_t flat = ((((size_t)b * GD + vz) * GH + vy) * GW + vx) * C_OUT;
        float* op = out + flat;
        #pragma unroll
        for (int c = 0; c < C_OUT; ++c) atomicAdd(op + c, accv[sl][c]);
    }
}

// ============================================================================
extern "C" void kernel_launch(void* const* d_in, const int* in_sizes, int n_in,
                              void* d_out, int out_size, void* d_ws, size_t ws_size,
                              hipStream_t stream) {
    const float* origins = (const float*)d_in[0];
    const float* dirs    = (const float*)d_in[1];
    const float* nearv   = (const float*)d_in[2];
    const float* farv    = (const float*)d_in[3];
    const float* enc     = (const float*)d_in[4];
    const int*   gidx    = (const int*)  d_in[5];
    const float* grid    = (const float*)d_in[6];
    const float* W0      = (const float*)d_in[7];
    const float* b0      = (const float*)d_in[8];
    const float* W1      = (const float*)d_in[9];
    const float* b1      = (const float*)d_in[10];
    float* out = (float*)d_out;

    const size_t PF_B = (size_t)M_PTS * 16;         // 25,165,824
    const size_t PO_B = (size_t)M_PTS * 64;         // 100,663,296
    const size_t EN_B = (size_t)M_PTS * 8 * 4;      // 50,331,648 (hard bound)
    const size_t CT_B = (size_t)NTILES * 4;
    const size_t NEED = PF_B + PO_B + EN_B + 3 * CT_B;

    if (ws_size < NEED) {
        // fallback: fused register-merged scatter (round-3 path)
        hipMemsetAsync(out, 0, (size_t)out_size * sizeof(float), stream);
        splat_seg_kernel<<<NTHREADS/256, 256, 0, stream>>>(
            origins, dirs, nearv, farv, enc, gidx, grid, W0, b0, W1, b1, out);
        return;
    }

    char* w = (char*)d_ws;
    float4*   pf      = (float4*)   w;              w += PF_B;
    float4*   po      = (float4*)   w;              w += PO_B;
    unsigned* entries = (unsigned*) w;              w += EN_B;
    unsigned* counts  = (unsigned*) w;              w += CT_B;
    unsigned* offsets = (unsigned*) w;              w += CT_B;
    unsigned* alloc   = (unsigned*) w;              w += CT_B;

    hipMemsetAsync(counts, 0, CT_B, stream);
    k1_point<<<M_PTS/256, 256, 0, stream>>>(origins, dirs, nearv, farv, enc, gidx,
                                            grid, W0, b0, W1, b1, pf, po, counts);
    k2_scan<<<1, 256, 0, stream>>>(counts, offsets, alloc);
    k3_scatter<<<M_PTS/256, 256, 0, stream>>>(pf, alloc, entries);
    k4_accum<<<NTILES, 256, 0, stream>>>(pf, po, entries, offsets, alloc, out);
    // K4 writes every output voxel densely -> no output memset needed.
}

// Round 10
// 671.833 us; speedup vs baseline: 2.9508x; 1.3179x over previous
//
#include <hip/hip_runtime.h>

#define N_RAYS 16384
#define NSAMP  96
#define GD 128
#define GH 128
#define GW 128
#define C_IN  32
#define C_HID 32
#define C_OUT 16
#define M_PTS (N_RAYS * NSAMP)       // 1,572,864 (divisible by 256)
#define TPA 16                        // tiles per axis (128/8)
#define NTILES (TPA*TPA*TPA)          // 4096
#define TW 8                          // tile width (voxels)
#define TVOX (TW*TW*TW)               // 512 voxels per tile
#define CHUNK 128                     // entries staged per K4 inner pass

__device__ __forceinline__ int clampi(int v, int hi) { return min(max(v, 0), hi); }

struct TileSpan { int txa, txb, tya, tyb, tza, tzb; };
__device__ __forceinline__ TileSpan tile_span(int X, int Y, int Z) {
    TileSpan s;
    s.txa = clampi(X,   GW-1) >> 3;  s.txb = clampi(X+1, GW-1) >> 3;
    s.tya = clampi(Y,   GH-1) >> 3;  s.tyb = clampi(Y+1, GH-1) >> 3;
    s.tza = clampi(Z,   GD-1) >> 3;  s.tzb = clampi(Z+1, GD-1) >> 3;
    return s;
}

// ============================================================================
// K1: per-point gather + MLP. Stores o[16] (planar float4) + frac/key, and
// accumulates per-tile point counts (LDS histogram -> global atomicAdd).
// ============================================================================
__global__ __launch_bounds__(256) void k1_point(
    const float* __restrict__ origins, const float* __restrict__ dirs,
    const float* __restrict__ nearv,   const float* __restrict__ farv,
    const float* __restrict__ enc,     const int*   __restrict__ gidx,
    const float* __restrict__ grid,    const float* __restrict__ W0,
    const float* __restrict__ b0,      const float* __restrict__ W1,
    const float* __restrict__ b1,
    float4* __restrict__ pf, float4* __restrict__ po, unsigned* __restrict__ counts)
{
    __shared__ unsigned lcnt[NTILES];
    for (int i = threadIdx.x; i < NTILES; i += 256) lcnt[i] = 0;
    __syncthreads();

    int pid = blockIdx.x * 256 + threadIdx.x;     // always < M_PTS (exact grid)
    int ray = pid / NSAMP;
    int s   = pid - ray * NSAMP;

    float nr = nearv[ray], fr = farv[ray];
    float t  = nr + (fr - nr) * ((float)s * (1.0f / (NSAMP - 1)));
    float px = fmaf(t, dirs[ray*3+0], origins[ray*3+0]);
    float py = fmaf(t, dirs[ray*3+1], origins[ray*3+1]);
    float pz = fmaf(t, dirs[ray*3+2], origins[ray*3+2]);
    int   b  = gidx[ray];

    float cx = ((px + 1.0f) * (float)GW - 1.0f) * 0.5f;
    float cy = ((py + 1.0f) * (float)GH - 1.0f) * 0.5f;
    float cz = ((pz + 1.0f) * (float)GD - 1.0f) * 0.5f;
    float fxf = floorf(cx), fyf = floorf(cy), fzf = floorf(cz);
    float fx = cx - fxf, fy = cy - fyf, fz = cz - fzf;
    int X = (int)fxf, Y = (int)fyf, Z = (int)fzf;

    // ---- trilinear gather (feat starts at ray encoding) ----
    float feat[C_IN];
    {
        const float4* e4 = (const float4*)(enc + (size_t)ray * C_IN);
        #pragma unroll
        for (int q = 0; q < C_IN/4; ++q) {
            float4 v = e4[q];
            feat[4*q+0] = v.x; feat[4*q+1] = v.y; feat[4*q+2] = v.z; feat[4*q+3] = v.w;
        }
    }
    int gx[2] = { clampi(X, GW-1), clampi(X+1, GW-1) };
    int gy[2] = { clampi(Y, GH-1), clampi(Y+1, GH-1) };
    int gz[2] = { clampi(Z, GD-1), clampi(Z+1, GD-1) };
    float wxa[2] = { 1.0f - fx, fx };
    float wya[2] = { 1.0f - fy, fy };
    float wza[2] = { 1.0f - fz, fz };
    #pragma unroll
    for (int dz = 0; dz < 2; ++dz)
    #pragma unroll
    for (int dy = 0; dy < 2; ++dy)
    #pragma unroll
    for (int dx = 0; dx < 2; ++dx) {
        float w = wza[dz] * wya[dy] * wxa[dx];
        size_t flat = ((((size_t)b * GD + gz[dz]) * GH + gy[dy]) * GW + gx[dx]) * C_IN;
        const float4* g4 = (const float4*)(grid + flat);
        #pragma unroll
        for (int q = 0; q < C_IN/4; ++q) {
            float4 v = g4[q];
            feat[4*q+0] = fmaf(w, v.x, feat[4*q+0]);
            feat[4*q+1] = fmaf(w, v.y, feat[4*q+1]);
            feat[4*q+2] = fmaf(w, v.z, feat[4*q+2]);
            feat[4*q+3] = fmaf(w, v.w, feat[4*q+3]);
        }
    }

    // ---- MLP (weights wave-uniform -> scalar loads) ----
    float h[C_HID];
    #pragma unroll
    for (int j = 0; j < C_HID; ++j) h[j] = b0[j];
    #pragma unroll
    for (int i = 0; i < C_IN; ++i) {
        float xi = feat[i];
        #pragma unroll
        for (int j = 0; j < C_HID; ++j) h[j] = fmaf(xi, W0[i*C_HID + j], h[j]);
    }
    #pragma unroll
    for (int j = 0; j < C_HID; ++j) h[j] = fmaxf(h[j], 0.0f);

    float o[C_OUT];
    #pragma unroll
    for (int j = 0; j < C_OUT; ++j) o[j] = b1[j];
    #pragma unroll
    for (int i = 0; i < C_HID; ++i) {
        float hi = h[i];
        #pragma unroll
        for (int j = 0; j < C_OUT; ++j) o[j] = fmaf(hi, W1[i*C_OUT + j], o[j]);
    }

    // ---- store point record (planar, coalesced) ----
    unsigned key = ((unsigned)(X + 256) & 511u)
                 | (((unsigned)(Y + 256) & 511u) << 9)
                 | (((unsigned)(Z + 256) & 511u) << 18);
    pf[pid] = make_float4(fx, fy, fz, __uint_as_float(key));
    #pragma unroll
    for (int q = 0; q < 4; ++q)
        po[(size_t)q * M_PTS + pid] = make_float4(o[4*q+0], o[4*q+1], o[4*q+2], o[4*q+3]);

    // ---- count touched tiles ----
    TileSpan ts = tile_span(X, Y, Z);
    #pragma unroll
    for (int ez = 0; ez < 2; ++ez) {
        if (ez && ts.tzb == ts.tza) continue;
        #pragma unroll
        for (int ey = 0; ey < 2; ++ey) {
            if (ey && ts.tyb == ts.tya) continue;
            #pragma unroll
            for (int ex = 0; ex < 2; ++ex) {
                if (ex && ts.txb == ts.txa) continue;
                int tt = ((ts.tza + ez) * TPA + (ts.tya + ey)) * TPA + (ts.txa + ex);
                atomicAdd(&lcnt[tt], 1u);
            }
        }
    }
    __syncthreads();
    for (int i = threadIdx.x; i < NTILES; i += 256)
        if (lcnt[i]) atomicAdd(&counts[i], lcnt[i]);
}

// ============================================================================
// K2: exclusive scan of 4096 tile counts + heavy-first tile schedule.
// order[] = tiles sorted by count descending (256-bucket counting sort).
// Slot assignment within a bucket is nondeterministic but output sums are
// order-independent, so results stay deterministic.
// ============================================================================
__global__ __launch_bounds__(256) void k2_scan(
    const unsigned* __restrict__ counts,
    unsigned* __restrict__ offsets, unsigned* __restrict__ alloc,
    unsigned* __restrict__ order)
{
    __shared__ unsigned psum[256];
    __shared__ unsigned bh[256];     // bucket histogram (count>>4, capped)
    __shared__ unsigned bb[256];     // bucket base (descending order)
    int tid = threadIdx.x;
    unsigned base = tid * 16;
    unsigned ssum = 0;
    for (int i = 0; i < 16; ++i) ssum += counts[base + i];
    psum[tid] = ssum;
    bh[tid] = 0;
    __syncthreads();
    if (tid == 0) {
        unsigned r = 0;
        for (int i = 0; i < 256; ++i) { unsigned v = psum[i]; psum[i] = r; r += v; }
    }
    __syncthreads();
    unsigned run = psum[tid];
    for (int i = 0; i < 16; ++i) {
        unsigned v = counts[base + i];
        offsets[base + i] = run;
        alloc[base + i]   = run;
        run += v;
        atomicAdd(&bh[min(v >> 4, 255u)], 1u);
    }
    __syncthreads();
    if (tid == 0) {
        unsigned r = 0;
        for (int b = 255; b >= 0; --b) { unsigned v = bh[b]; bb[b] = r; r += v; }
    }
    __syncthreads();
    for (int i = 0; i < 16; ++i) {
        unsigned v = counts[base + i];
        unsigned slot = atomicAdd(&bb[min(v >> 4, 255u)], 1u);
        order[slot] = base + i;
    }
}

// ============================================================================
// K3: scatter point indices into per-tile segments. Block-local LDS histogram
// + rank, one global atomicAdd per (block, nonzero tile) for segment alloc.
// ============================================================================
__global__ __launch_bounds__(256) void k3_scatter(
    const float4* __restrict__ pf, unsigned* __restrict__ alloc,
    unsigned* __restrict__ entries)
{
    __shared__ unsigned lcnt[NTILES];
    __shared__ unsigned lbase[NTILES];
    for (int i = threadIdx.x; i < NTILES; i += 256) lcnt[i] = 0;
    __syncthreads();

    int pid = blockIdx.x * 256 + threadIdx.x;
    float4 f = pf[pid];
    unsigned key = __float_as_uint(f.w);
    int X = (int)(key & 511u) - 256;
    int Y = (int)((key >> 9) & 511u) - 256;
    int Z = (int)((key >> 18) & 511u) - 256;
    TileSpan ts = tile_span(X, Y, Z);

    unsigned rnk[2][2][2];
    #pragma unroll
    for (int ez = 0; ez < 2; ++ez) {
        bool okz = (ez == 0) || (ts.tzb > ts.tza);
        #pragma unroll
        for (int ey = 0; ey < 2; ++ey) {
            bool oky = (ey == 0) || (ts.tyb > ts.tya);
            #pragma unroll
            for (int ex = 0; ex < 2; ++ex) {
                bool okx = (ex == 0) || (ts.txb > ts.txa);
                if (okz && oky && okx) {
                    int tt = ((ts.tza + ez) * TPA + (ts.tya + ey)) * TPA + (ts.txa + ex);
                    rnk[ez][ey][ex] = atomicAdd(&lcnt[tt], 1u);
                }
            }
        }
    }
    __syncthreads();
    for (int i = threadIdx.x; i < NTILES; i += 256)
        if (lcnt[i]) lbase[i] = atomicAdd(&alloc[i], lcnt[i]);
    __syncthreads();
    #pragma unroll
    for (int ez = 0; ez < 2; ++ez) {
        bool okz = (ez == 0) || (ts.tzb > ts.tza);
        #pragma unroll
        for (int ey = 0; ey < 2; ++ey) {
            bool oky = (ey == 0) || (ts.tyb > ts.tya);
            #pragma unroll
            for (int ex = 0; ex < 2; ++ex) {
                bool okx = (ex == 0) || (ts.txb > ts.txa);
                if (okz && oky && okx) {
                    int tt = ((ts.tza + ez) * TPA + (ts.tya + ey)) * TPA + (ts.txa + ex);
                    entries[lbase[tt] + rnk[ez][ey][ex]] = (unsigned)pid;
                }
            }
        }
    }
}

// ============================================================================
// K4: register accumulation + batched wave-uniform z skip + heavy-first
// schedule + wave-uniform per-layer FMA guards. Wave w owns z-layers
// {2w, 2w+1}; lane owns (x,y); 2x16 fp32 register accumulators. Entries whose
// z-span misses the wave are skipped via the int4 sZ scan; entries hitting
// only one of the wave's layers skip the other 16-FMA half (st*/l* are
// wave-uniform). Dense float4 writeback replaces the output memset.
// ============================================================================
__global__ __launch_bounds__(256) void k4_accum(
    const float4* __restrict__ pf, const float4* __restrict__ po,
    const unsigned* __restrict__ entries, const unsigned* __restrict__ offsets,
    const unsigned* __restrict__ alloc, const unsigned* __restrict__ order,
    float* __restrict__ out)
{
    __shared__ __attribute__((aligned(16))) float4 sA[CHUNK]; // fx,fy,fz, cx0|cx1|cy0|cy1
    __shared__ __attribute__((aligned(16))) int    sZ[CHUNK]; // st0|st1<<8 (255=out)
    __shared__ __attribute__((aligned(16))) float4 sO[4*CHUNK]; // o[16] planar [q][entry]

    int t  = order[blockIdx.x];      // heavy tiles scheduled first
    int tx = t & (TPA-1), ty = (t >> 4) & (TPA-1), tz = t >> 8;
    int ox = tx * TW, oy = ty * TW, oz = tz * TW;

    int tid  = threadIdx.x;
    int lane = tid & 63;
    int w    = tid >> 6;             // wave id, owns z-layers {2w, 2w+1}
    int vxa  = ox + (lane & 7);      // absolute voxel coords this lane owns
    int vya  = oy + (lane >> 3);
    int l0   = 2*w, l1 = 2*w + 1;    // tile-relative z layers

    float accA[C_OUT], accB[C_OUT];
    #pragma unroll
    for (int c = 0; c < C_OUT; ++c) { accA[c] = 0.0f; accB[c] = 0.0f; }

    unsigned e0 = offsets[t], e1 = alloc[t];
    for (unsigned base = e0; base < e1; base += CHUNK) {
        int n = min((unsigned)CHUNK, e1 - base);
        if (tid < CHUNK) {
            if (tid < n) {
                unsigned p = entries[base + tid];
                float4 f = pf[p];
                unsigned key = __float_as_uint(f.w);
                int X = (int)(key & 511u) - 256;
                int Y = (int)((key >> 9) & 511u) - 256;
                int Z = (int)((key >> 18) & 511u) - 256;
                int cx0 = clampi(X, GW-1),  cx1 = clampi(X+1, GW-1);
                int cy0 = clampi(Y, GH-1),  cy1 = clampi(Y+1, GH-1);
                int cz0 = clampi(Z, GD-1),  cz1 = clampi(Z+1, GD-1);
                unsigned pk = (unsigned)cx0 | ((unsigned)cx1 << 8)
                            | ((unsigned)cy0 << 16) | ((unsigned)cy1 << 24);
                int st0 = ((unsigned)(cz0 - oz) < 8u) ? (cz0 - oz) : 255;
                int st1 = ((unsigned)(cz1 - oz) < 8u) ? (cz1 - oz) : 255;
                sA[tid] = make_float4(f.x, f.y, f.z, __uint_as_float(pk));
                sZ[tid] = st0 | (st1 << 8);
                #pragma unroll
                for (int q = 0; q < 4; ++q)
                    sO[q*CHUNK + tid] = po[(size_t)q * M_PTS + p];
            } else {
                sZ[tid] = 255 | (255 << 8);   // sentinel: hits no wave
            }
        }
        __syncthreads();

        const int4* sZ4 = (const int4*)sZ;
        int n4 = (n + 3) & ~3;
        for (int jb = 0; jb < n4; jb += 4) {
            int4 z4 = sZ4[jb >> 2];                     // broadcast batch of 4
            #pragma unroll
            for (int k = 0; k < 4; ++k) {
                int zz  = (k==0) ? z4.x : (k==1) ? z4.y : (k==2) ? z4.z : z4.w;
                int st0 = zz & 255, st1 = (zz >> 8) & 255;
                bool hitA = (st0 == l0) | (st1 == l0);   // wave-uniform
                bool hitB = (st0 == l1) | (st1 == l1);   // wave-uniform
                if (!(hitA | hitB)) continue;            // uniform skip
                int j = jb + k;
                float4 a = sA[j];                        // b128 broadcast
                unsigned pk = __float_as_uint(a.w);
                int cx0 = (int)(pk & 255u),         cx1 = (int)((pk >> 8) & 255u);
                int cy0 = (int)((pk >> 16) & 255u), cy1 = (int)(pk >> 24);

                // '==' both corners: collapse at borders sums both weights
                float wx = ((vxa == cx0) ? 1.0f - a.x : 0.0f)
                         + ((vxa == cx1) ? a.x        : 0.0f);
                float wy = ((vya == cy0) ? 1.0f - a.y : 0.0f)
                         + ((vya == cy1) ? a.y        : 0.0f);
                float wxy = wx * wy;

                if (hitA) {                              // wave-uniform branch
                    float wzA = ((st0 == l0) ? 1.0f - a.z : 0.0f)
                              + ((st1 == l0) ? a.z        : 0.0f);
                    float wA = wxy * wzA;
                    #pragma unroll
                    for (int q = 0; q < 4; ++q) {
                        float4 ov = sO[q*CHUNK + j];
                        accA[4*q+0] = fmaf(wA, ov.x, accA[4*q+0]);
                        accA[4*q+1] = fmaf(wA, ov.y, accA[4*q+1]);
                        accA[4*q+2] = fmaf(wA, ov.z, accA[4*q+2]);
                        accA[4*q+3] = fmaf(wA, ov.w, accA[4*q+3]);
                    }
                }
                if (hitB) {                              // wave-uniform branch
                    float wzB = ((st0 == l1) ? 1.0f - a.z : 0.0f)
                              + ((st1 == l1) ? a.z        : 0.0f);
                    float wB = wxy * wzB;
                    #pragma unroll
                    for (int q = 0; q < 4; ++q) {
                        float4 ov = sO[q*CHUNK + j];
                        accB[4*q+0] = fmaf(wB, ov.x, accB[4*q+0]);
                        accB[4*q+1] = fmaf(wB, ov.y, accB[4*q+1]);
                        accB[4*q+2] = fmaf(wB, ov.z, accB[4*q+2]);
                        accB[4*q+3] = fmaf(wB, ov.w, accB[4*q+3]);
                    }
                }
            }
        }
        __syncthreads();
    }

    // ---- dense register writeback (full coverage -> no memset needed) ----
    size_t baseA = ((((size_t)(oz + l0)) * GH + vya) * GW + vxa) * C_OUT;
    size_t baseB = ((((size_t)(oz + l1)) * GH + vya) * GW + vxa) * C_OUT;
    #pragma unroll
    for (int q = 0; q < 4; ++q) {
        *(float4*)(out + baseA + 4*q) = make_float4(accA[4*q+0], accA[4*q+1], accA[4*q+2], accA[4*q+3]);
        *(float4*)(out + baseB + 4*q) = make_float4(accB[4*q+0], accB[4*q+1], accB[4*q+2], accB[4*q+3]);
    }
}

// ============================================================================
// Fallback (round-3 fused kernel) if workspace is too small.
// ============================================================================
#define SEGS   8
#define SEGLEN (NSAMP / SEGS)
#define NTHREADS (N_RAYS * SEGS)

__global__ __launch_bounds__(256, 2) void splat_seg_kernel(
    const float* __restrict__ origins, const float* __restrict__ dirs,
    const float* __restrict__ nearv,   const float* __restrict__ farv,
    const float* __restrict__ enc,     const int*   __restrict__ gidx,
    const float* __restrict__ grid,    const float* __restrict__ W0,
    const float* __restrict__ b0,      const float* __restrict__ W1,
    const float* __restrict__ b1,      float* __restrict__ out)
{
    int tid = blockIdx.x * blockDim.x + threadIdx.x;
    if (tid >= NTHREADS) return;
    int ray = tid / SEGS;
    int seg = tid - ray * SEGS;
    float nr = nearv[ray], fr = farv[ray];
    float ox = origins[3*ray+0], oy = origins[3*ray+1], oz = origins[3*ray+2];
    float rdx = dirs[3*ray+0],   rdy = dirs[3*ray+1],   rdz = dirs[3*ray+2];
    int   b  = gidx[ray];
    float accv[8][C_OUT];
    #pragma unroll
    for (int sl = 0; sl < 8; ++sl)
        #pragma unroll
        for (int c = 0; c < C_OUT; ++c) accv[sl][c] = 0.0f;
    int Xp = 0, Yp = 0, Zp = 0;
    #pragma unroll 1
    for (int k = 0; k < SEGLEN; ++k) {
        int s = seg * SEGLEN + k;
        float t  = nr + (fr - nr) * ((float)s * (1.0f / (NSAMP - 1)));
        float px = fmaf(t, rdx, ox);
        float py = fmaf(t, rdy, oy);
        float pz = fmaf(t, rdz, oz);
        float cx = ((px + 1.0f) * (float)GW - 1.0f) * 0.5f;
        float cy = ((py + 1.0f) * (float)GH - 1.0f) * 0.5f;
        float cz = ((pz + 1.0f) * (float)GD - 1.0f) * 0.5f;
        float fxf = floorf(cx), fyf = floorf(cy), fzf = floorf(cz);
        float fx = cx - fxf, fy = cy - fyf, fz = cz - fzf;
        int X = (int)fxf, Y = (int)fyf, Z = (int)fzf;
        if (k == 0) { Xp = X; Yp = Y; Zp = Z; }
        else if (X != Xp || Y != Yp || Z != Zp) {
            bool fXm[2], fYm[2], fZm[2];
            int  vx[2], vy[2], vz[2];
            #pragma unroll
            for (int p = 0; p < 2; ++p) {
                int xo = Xp + ((Xp ^ p) & 1), xn = X + ((X ^ p) & 1);
                fXm[p] = (xo != xn);  vx[p] = clampi(xo, GW-1);
                int yo = Yp + ((Yp ^ p) & 1), yn = Y + ((Y ^ p) & 1);
                fYm[p] = (yo != yn);  vy[p] = clampi(yo, GH-1);
                int zo = Zp + ((Zp ^ p) & 1), zn = Z + ((Z ^ p) & 1);
                fZm[p] = (zo != zn);  vz[p] = clampi(zo, GD-1);
            }
            #pragma unroll
            for (int pxi = 0; pxi < 2; ++pxi)
            #pragma unroll
            for (int pyi = 0; pyi < 2; ++pyi)
            #pragma unroll
            for (int pzi = 0; pzi < 2; ++pzi) {
                const int sl = pxi*4 + pyi*2 + pzi;
                if (fXm[pxi] | fYm[pyi] | fZm[pzi]) {
                    size_t flat = ((((size_t)b * GD + vz[pzi]) * GH + vy[pyi]) * GW + vx[pxi]) * C_OUT;
                    float* op = out + flat;
                    #pragma unroll
                    for (int c = 0; c < C_OUT; ++c) { atomicAdd(op + c, accv[sl][c]); accv[sl][c] = 0.0f; }
                }
            }
            Xp = X; Yp = Y; Zp = Z;
        }
        float feat[C_IN];
        {
            const float4* e4 = (const float4*)(enc + (size_t)ray * C_IN);
            #pragma unroll
            for (int q = 0; q < C_IN/4; ++q) {
                float4 v = e4[q];
                feat[4*q+0] = v.x; feat[4*q+1] = v.y; feat[4*q+2] = v.z; feat[4*q+3] = v.w;
            }
        }
        int gx[2] = { clampi(X, GW-1), clampi(X+1, GW-1) };
        int gy[2] = { clampi(Y, GH-1), clampi(Y+1, GH-1) };
        int gz[2] = { clampi(Z, GD-1), clampi(Z+1, GD-1) };
        float wxa[2] = { 1.0f - fx, fx };
        float wya[2] = { 1.0f - fy, fy };
        float wza[2] = { 1.0f - fz, fz };
        #pragma unroll
        for (int dz = 0; dz < 2; ++dz)
        #pragma unroll
        for (int dy = 0; dy < 2; ++dy)
        #pragma unroll
        for (int dx = 0; dx < 2; ++dx) {
            float w = wza[dz] * wya[dy] * wxa[dx];
            size_t flat = ((((size_t)b * GD + gz[dz]) * GH + gy[dy]) * GW + gx[dx]) * C_IN;
            const float4* g4 = (const float4*)(grid + flat);
            #pragma unroll
            for (int q = 0; q < C_IN/4; ++q) {
                float4 v = g4[q];
                feat[4*q+0] = fmaf(w, v.x, feat[4*q+0]);
                feat[4*q+1] = fmaf(w, v.y, feat[4*q+1]);
                feat[4*q+2] = fmaf(w, v.z, feat[4*q+2]);
                feat[4*q+3] = fmaf(w, v.w, feat[4*q+3]);
            }
        }
        float h[C_HID];
        #pragma unroll
        for (int j = 0; j < C_HID; ++j) h[j] = b0[j];
        #pragma unroll
        for (int i = 0; i < C_IN; ++i) {
            float xi = feat[i];
            #pragma unroll
            for (int j = 0; j < C_HID; ++j) h[j] = fmaf(xi, W0[i*C_HID + j], h[j]);
        }
        #pragma unroll
        for (int j = 0; j < C_HID; ++j) h[j] = fmaxf(h[j], 0.0f);
        float o[C_OUT];
        #pragma unroll
        for (int j = 0; j < C_OUT; ++j) o[j] = b1[j];
        #pragma unroll
        for (int i = 0; i < C_HID; ++i) {
            float hi = h[i];
            #pragma unroll
            for (int j = 0; j < C_OUT; ++j) o[j] = fmaf(hi, W1[i*C_OUT + j], o[j]);
        }
        float wxs[2], wys[2], wzs[2];
        #pragma unroll
        for (int p = 0; p < 2; ++p) {
            wxs[p] = ((X & 1) == p) ? (1.0f - fx) : fx;
            wys[p] = ((Y & 1) == p) ? (1.0f - fy) : fy;
            wzs[p] = ((Z & 1) == p) ? (1.0f - fz) : fz;
        }
        #pragma unroll
        for (int pxi = 0; pxi < 2; ++pxi)
        #pragma unroll
        for (int pyi = 0; pyi < 2; ++pyi)
        #pragma unroll
        for (int pzi = 0; pzi < 2; ++pzi) {
            const int sl = pxi*4 + pyi*2 + pzi;
            float w = wxs[pxi] * wys[pyi] * wzs[pzi];
            #pragma unroll
            for (int c = 0; c < C_OUT; ++c) accv[sl][c] = fmaf(w, o[c], accv[sl][c]);
        }
    }
    #pragma unroll
    for (int pxi = 0; pxi < 2; ++pxi)
    #pragma unroll
    for (int pyi = 0; pyi < 2; ++pyi)
    #pragma unroll
    for (int pzi = 0; pzi < 2; ++pzi) {
        const int sl = pxi*4 + pyi*2 + pzi;
        int vx = clampi(Xp + ((Xp ^ pxi) & 1), GW-1);
        int vy = clampi(Yp + ((Yp ^ pyi) & 1), GH-1);
        int vz = clampi(Zp + ((Zp ^ pzi) & 1), GD-1);
        size_t flat = ((((size_t)b * GD + vz) * GH + vy) * GW + vx) * C_OUT;
        float* op = out + flat;
        #pragma unroll
        for (int c = 0; c < C_OUT; ++c) atomicAdd(op + c, accv[sl][c]);
    }
}

// ============================================================================
extern "C" void kernel_launch(void* const* d_in, const int* in_sizes, int n_in,
                              void* d_out, int out_size, void* d_ws, size_t ws_size,
                              hipStream_t stream) {
    const float* origins = (const float*)d_in[0];
    const float* dirs    = (const float*)d_in[1];
    const float* nearv   = (const float*)d_in[2];
    const float* farv    = (const float*)d_in[3];
    const float* enc     = (const float*)d_in[4];
    const int*   gidx    = (const int*)  d_in[5];
    const float* grid    = (const float*)d_in[6];
    const float* W0      = (const float*)d_in[7];
    const float* b0      = (const float*)d_in[8];
    const float* W1      = (const float*)d_in[9];
    const float* b1      = (const float*)d_in[10];
    float* out = (float*)d_out;

    const size_t PF_B = (size_t)M_PTS * 16;         // 25,165,824
    const size_t PO_B = (size_t)M_PTS * 64;         // 100,663,296
    const size_t EN_B = (size_t)M_PTS * 8 * 4;      // 50,331,648 (hard bound)
    const size_t CT_B = (size_t)NTILES * 4;
    const size_t NEED = PF_B + PO_B + EN_B + 4 * CT_B;

    if (ws_size < NEED) {
        // fallback: fused register-merged scatter (round-3 path)
        hipMemsetAsync(out, 0, (size_t)out_size * sizeof(float), stream);
        splat_seg_kernel<<<NTHREADS/256, 256, 0, stream>>>(
            origins, dirs, nearv, farv, enc, gidx, grid, W0, b0, W1, b1, out);
        return;
    }

    char* w = (char*)d_ws;
    float4*   pf      = (float4*)   w;              w += PF_B;
    float4*   po      = (float4*)   w;              w += PO_B;
    unsigned* entries = (unsigned*) w;              w += EN_B;
    unsigned* counts  = (unsigned*) w;              w += CT_B;
    unsigned* offsets = (unsigned*) w;              w += CT_B;
    unsigned* alloc   = (unsigned*) w;              w += CT_B;
    unsigned* order   = (unsigned*) w;              w += CT_B;

    hipMemsetAsync(counts, 0, CT_B, stream);
    k1_point<<<M_PTS/256, 256, 0, stream>>>(origins, dirs, nearv, farv, enc, gidx,
                                            grid, W0, b0, W1, b1, pf, po, counts);
    k2_scan<<<1, 256, 0, stream>>>(counts, offsets, alloc, order);
    k3_scatter<<<M_PTS/256, 256, 0, stream>>>(pf, alloc, entries);
    k4_accum<<<NTILES, 256, 0, stream>>>(pf, po, entries, offsets, alloc, order, out);
    // K4 writes every output voxel densely -> no output memset needed.
}